// Round 3
// baseline (450.121 us; speedup 1.0000x reference)
//
#include <hip/hip_runtime.h>

#define T_TOK 4096
#define H_DIM 2048
#define I_DIM 768
#define E_NUM 8

typedef __attribute__((ext_vector_type(8))) short bf16x8;
typedef __attribute__((ext_vector_type(4))) float f32x4;

__device__ __forceinline__ unsigned short f2bf(float f) {
  union { float f; unsigned int u; } c; c.f = f;
  unsigned int r = c.u + 0x7fffu + ((c.u >> 16) & 1u);
  return (unsigned short)(r >> 16);
}

// async global->LDS DMA, 16B per lane; lds dest = wave-uniform base + lane*16
__device__ __forceinline__ void gl_lds16(const unsigned short* g, unsigned short* l) {
  __builtin_amdgcn_global_load_lds(
      (const __attribute__((address_space(1))) unsigned int*)g,
      (__attribute__((address_space(3))) unsigned int*)l, 16, 0, 0);
}

// ---------------- weights: f32 [E][K][N] -> bf16 [E][N][K] ----------------
__global__ __launch_bounds__(256) void transpose_cast_kernel(
    const float* __restrict__ src, unsigned short* __restrict__ dst,
    int K, int N)
{
  const int e = blockIdx.z;
  const int kb = blockIdx.y * 64, nb = blockIdx.x * 64;
  src += (size_t)e * K * N + (size_t)kb * N + nb;
  dst += (size_t)e * N * K + (size_t)nb * K + kb;
  __shared__ float tile[64][65];
  const int tid = threadIdx.x;
  const int lr = tid >> 4, lc = (tid & 15) * 4;
#pragma unroll
  for (int it = 0; it < 4; ++it) {
    float4 v = *(const float4*)(src + (size_t)(lr + it * 16) * N + lc);
    tile[lr + it * 16][lc]     = v.x;
    tile[lr + it * 16][lc + 1] = v.y;
    tile[lr + it * 16][lc + 2] = v.z;
    tile[lr + it * 16][lc + 3] = v.w;
  }
  __syncthreads();
  const int wn = tid >> 2, wk = (tid & 3) * 16;
  union { uint4 u[2]; unsigned short h[16]; } o;
#pragma unroll
  for (int j = 0; j < 16; ++j) o.h[j] = f2bf(tile[wk + j][wn]);
  *(uint4*)(dst + (size_t)wn * K + wk)     = o.u[0];
  *(uint4*)(dst + (size_t)wn * K + wk + 8) = o.u[1];
}

// ---------------- Router (+ fused x f32->bf16 cast) ----------------
// 8 tokens per block, w_router slice cached in registers, block-aggregated
// atomics (<=8 per block instead of 2 dependent per token).
#define RTOK 8
__global__ __launch_bounds__(256) void router_kernel(
    const float* __restrict__ x,               // [T,H] f32
    const float* __restrict__ wr,              // [H,E] f32
    unsigned short* __restrict__ xbf,          // [T,H] bf16 out
    float* __restrict__ logits_out,            // [T,E] f32 (d_out tail)
    int* __restrict__ counts,                  // [E]
    int* __restrict__ entries,                 // [E][T] pair-slot p = t*2+k
    float* __restrict__ entry_w)               // [E][T]
{
  const int tid = threadIdx.x;
  const int w = tid >> 6, lane = tid & 63;
  const int t0 = blockIdx.x * RTOK;
  const int hb = w * 512 + lane * 8;           // this thread's H-chunk base

  // cache this thread's 8 rows x 8 experts of w_router in registers (64 VGPR)
  float wreg[8][8];
#pragma unroll
  for (int r = 0; r < 8; ++r) {
    *(float4*)&wreg[r][0] = *(const float4*)(wr + (size_t)(hb + r) * E_NUM);
    *(float4*)&wreg[r][4] = *(const float4*)(wr + (size_t)(hb + r) * E_NUM + 4);
  }

  __shared__ float red[RTOK][4][E_NUM];        // wave partials
  __shared__ float lg[RTOK][E_NUM];            // logits
  __shared__ int   ch_i[RTOK][2];
  __shared__ float ch_w[RTOK][2];

  for (int tt = 0; tt < RTOK; ++tt) {
    const int t = t0 + tt;
    float xv[8];
    *(float4*)&xv[0] = *(const float4*)(x + (size_t)t * H_DIM + hb);
    *(float4*)&xv[4] = *(const float4*)(x + (size_t)t * H_DIM + hb + 4);
    // fused cast of this x chunk to bf16 (16B/lane, fully coalesced)
    union { uint4 u; unsigned short h[8]; } o;
#pragma unroll
    for (int j = 0; j < 8; ++j) o.h[j] = f2bf(xv[j]);
    *(uint4*)(xbf + (size_t)t * H_DIM + hb) = o.u;

    float acc[E_NUM];
#pragma unroll
    for (int e = 0; e < E_NUM; ++e) acc[e] = 0.f;
#pragma unroll
    for (int r = 0; r < 8; ++r)
#pragma unroll
      for (int e = 0; e < E_NUM; ++e) acc[e] = fmaf(xv[r], wreg[r][e], acc[e]);
#pragma unroll
    for (int off = 32; off > 0; off >>= 1)
#pragma unroll
      for (int e = 0; e < E_NUM; ++e) acc[e] += __shfl_down(acc[e], off);
    if (lane == 0)
#pragma unroll
      for (int e = 0; e < E_NUM; ++e) red[tt][w][e] = acc[e];
  }
  __syncthreads();

  // 64 threads: finish logits (sum 4 wave partials), write logits_out
  if (tid < RTOK * E_NUM) {
    const int tt = tid >> 3, e = tid & 7;
    float l = red[tt][0][e] + red[tt][1][e] + red[tt][2][e] + red[tt][3][e];
    lg[tt][e] = l;
    logits_out[(size_t)(t0 + tt) * E_NUM + e] = l;
  }
  __syncthreads();

  // 8 threads: top-2 per token
  if (tid < RTOK) {
    const int tt = tid;
    float m1 = lg[tt][0]; int i1 = 0;
#pragma unroll
    for (int e = 1; e < E_NUM; ++e) if (lg[tt][e] > m1) { m1 = lg[tt][e]; i1 = e; }
    float m2 = -3.4e38f; int i2 = -1;
#pragma unroll
    for (int e = 0; e < E_NUM; ++e) if (e != i1 && lg[tt][e] > m2) { m2 = lg[tt][e]; i2 = e; }
    float w1 = 1.f / (1.f + __expf(m2 - m1));
    ch_i[tt][0] = i1; ch_i[tt][1] = i2;
    ch_w[tt][0] = w1; ch_w[tt][1] = 1.f - w1;
  }
  __syncthreads();

  // 8 threads (one per expert): aggregate block's pairs, ONE atomic per expert
  if (tid < E_NUM) {
    const int e = tid;
    int cnt = 0;
#pragma unroll
    for (int tt = 0; tt < RTOK; ++tt) {
      if (ch_i[tt][0] == e) ++cnt;
      if (ch_i[tt][1] == e) ++cnt;
    }
    if (cnt > 0) {
      int base = atomicAdd(&counts[e], cnt);
      int pos = 0;
#pragma unroll
      for (int tt = 0; tt < RTOK; ++tt) {
#pragma unroll
        for (int k = 0; k < 2; ++k) {
          if (ch_i[tt][k] == e) {
            entries[e * T_TOK + base + pos] = (t0 + tt) * 2 + k;
            entry_w[e * T_TOK + base + pos] = ch_w[tt][k];
            ++pos;
          }
        }
      }
    }
  }
}

// Fragment read from XOR-swizzled flat tile: row stride 64 shorts, chunk of 8
// physical chunk = logical ^ (row & 7)
#define FRAG(arr, row, cb) \
  (*(const bf16x8*)(&(arr)[((row) << 6) + ((((cb)) ^ ((row) & 7)) << 3)]))

// ---------------- Up-projection: act[p,:] = silu(x Wg) * (x Wu) ----------------
// v4: BM=64, BN=64, BK=64, double-buffered. LDS 48KB -> 3 blocks/CU resident,
// 1536 active blocks (was 768 @ 2/CU). Wave tile 32x32 (x both g,u).
__global__ __launch_bounds__(256) void moe_up_kernel(
    const unsigned short* __restrict__ xbf,   // [T,H] bf16
    const unsigned short* __restrict__ wgt,   // [E][I][H] bf16
    const unsigned short* __restrict__ wut,   // [E][I][H] bf16
    const int* __restrict__ counts,
    const int* __restrict__ entries,
    unsigned short* __restrict__ act)         // [2T, I] bf16
{
  const int e = blockIdx.z;
  const int cnt = counts[e];
  const int m0 = blockIdx.y * 64;
  if (m0 >= cnt) return;
  const int n0 = blockIdx.x * 64;
  const int tid = threadIdx.x;

  __shared__ __align__(16) unsigned short As[2][64 * 64];
  __shared__ __align__(16) unsigned short Bg[2][64 * 64];
  __shared__ __align__(16) unsigned short Bu[2][64 * 64];
  __shared__ int rowp[64];

  if (tid < 64) rowp[tid] = (m0 + tid < cnt) ? entries[e * T_TOK + m0 + tid] : -1;
  __syncthreads();

  const int w = tid >> 6, lane = tid & 63;
  const int lrow = lane >> 3, lchunk = lane & 7;
  const int jj = lchunk ^ lrow;              // swizzled global chunk (lane-const)

  const unsigned short* wg_e = wgt + (size_t)e * I_DIM * H_DIM + (size_t)n0 * H_DIM;
  const unsigned short* wu_e = wut + (size_t)e * I_DIM * H_DIM + (size_t)n0 * H_DIM;
  // 64 A-rows = 8 chunks of 8; wave w stages chunks w and 4+w. Same for B.
  const unsigned short* gA[2]; const unsigned short* gG[2]; const unsigned short* gU[2];
  int coff[2];
#pragma unroll
  for (int t2 = 0; t2 < 2; ++t2) {
    int r = (t2 * 4 + w) * 8 + lrow;         // 0..63
    int p = rowp[r];
    int tok = (p >= 0) ? (p >> 1) : 0;
    gA[t2] = xbf + (size_t)tok * H_DIM + jj * 8;
    gG[t2] = wg_e + (size_t)r * H_DIM + jj * 8;
    gU[t2] = wu_e + (size_t)r * H_DIM + jj * 8;
    coff[t2] = (t2 * 4 + w) * 512;           // 8 rows * 64 shorts
  }

  f32x4 accg[2][2], accu[2][2];
#pragma unroll
  for (int i = 0; i < 2; ++i)
#pragma unroll
    for (int j = 0; j < 2; ++j) {
      accg[i][j] = (f32x4){0.f, 0.f, 0.f, 0.f};
      accu[i][j] = (f32x4){0.f, 0.f, 0.f, 0.f};
    }

  const int msub = (w >> 1) * 32, nsub = (w & 1) * 32;
  const int fm = lane & 15, fq = lane >> 4;

  // prologue: stage tile 0 into buf 0
#pragma unroll
  for (int t2 = 0; t2 < 2; ++t2) {
    gl_lds16(gA[t2], &As[0][coff[t2]]);
    gl_lds16(gG[t2], &Bg[0][coff[t2]]);
    gl_lds16(gU[t2], &Bu[0][coff[t2]]);
  }
  __syncthreads();                            // drains vmcnt(0) + barrier

  int cur = 0;
  for (int kt = 0; kt < H_DIM; kt += 64) {
    const int nxt = cur ^ 1;
    if (kt + 64 < H_DIM) {                    // prefetch next tile (issue only)
#pragma unroll
      for (int t2 = 0; t2 < 2; ++t2) {
        gl_lds16(gA[t2] + kt + 64, &As[nxt][coff[t2]]);
        gl_lds16(gG[t2] + kt + 64, &Bg[nxt][coff[t2]]);
        gl_lds16(gU[t2] + kt + 64, &Bu[nxt][coff[t2]]);
      }
    }
    const unsigned short* Ac  = As[cur];
    const unsigned short* Bgc = Bg[cur];
    const unsigned short* Buc = Bu[cur];
#pragma unroll
    for (int ks = 0; ks < 64; ks += 32) {
      const int cb = (ks >> 3) + fq;
      bf16x8 a[2], bg[2], bu[2];
#pragma unroll
      for (int mi = 0; mi < 2; ++mi)
        a[mi] = FRAG(Ac, msub + mi * 16 + fm, cb);
#pragma unroll
      for (int ni = 0; ni < 2; ++ni) {
        bg[ni] = FRAG(Bgc, nsub + ni * 16 + fm, cb);
        bu[ni] = FRAG(Buc, nsub + ni * 16 + fm, cb);
      }
#pragma unroll
      for (int mi = 0; mi < 2; ++mi)
#pragma unroll
        for (int ni = 0; ni < 2; ++ni) {
          accg[mi][ni] = __builtin_amdgcn_mfma_f32_16x16x32_bf16(a[mi], bg[ni], accg[mi][ni], 0, 0, 0);
          accu[mi][ni] = __builtin_amdgcn_mfma_f32_16x16x32_bf16(a[mi], bu[ni], accu[mi][ni], 0, 0, 0);
        }
    }
    __syncthreads();                          // prefetch landed; reads done
    cur = nxt;
  }
#pragma unroll
  for (int mi = 0; mi < 2; ++mi) {
#pragma unroll
    for (int r = 0; r < 4; ++r) {
      int ml = msub + mi * 16 + fq * 4 + r;
      int p = rowp[ml];
      if (p < 0) continue;
      size_t base = (size_t)p * I_DIM + n0 + nsub + fm;
#pragma unroll
      for (int ni = 0; ni < 2; ++ni) {
        float g = accg[mi][ni][r];
        float u = accu[mi][ni][r];
        float h = g / (1.f + __expf(-g)) * u;
        act[base + ni * 16] = f2bf(h);
      }
    }
  }
}

// ---------------- Down-projection + weighted scatter-add into d_out ----------------
// v4: BM=64, BN=64, BK=64, double-buffered. LDS 32KB -> 5 blocks/CU resident,
// 4096 active blocks (was 1024 @ 2/CU).
__global__ __launch_bounds__(256) void moe_down_kernel(
    const unsigned short* __restrict__ act,   // [2T, I] bf16
    const unsigned short* __restrict__ wot,   // [E][H][I] bf16
    const int* __restrict__ counts,
    const int* __restrict__ entries,
    const float* __restrict__ entry_w,
    float* __restrict__ out)                  // [T,H] f32
{
  const int e = blockIdx.z;
  const int cnt = counts[e];
  const int m0 = blockIdx.y * 64;
  if (m0 >= cnt) return;
  const int n0 = blockIdx.x * 64;
  const int tid = threadIdx.x;

  __shared__ __align__(16) unsigned short As[2][64 * 64];
  __shared__ __align__(16) unsigned short Bt[2][64 * 64];
  __shared__ int rowp[64];
  __shared__ float roww[64];

  if (tid < 64) {
    int idx = m0 + tid;
    rowp[tid] = (idx < cnt) ? entries[e * T_TOK + idx] : -1;
    roww[tid] = (idx < cnt) ? entry_w[e * T_TOK + idx] : 0.f;
  }
  __syncthreads();

  const int w = tid >> 6, lane = tid & 63;
  const int lrow = lane >> 3, lchunk = lane & 7;
  const int jj = lchunk ^ lrow;

  const unsigned short* wo_e = wot + (size_t)e * H_DIM * I_DIM + (size_t)n0 * I_DIM;
  const unsigned short* gA[2]; const unsigned short* gB[2];
  int coff[2];
#pragma unroll
  for (int t2 = 0; t2 < 2; ++t2) {
    int r = (t2 * 4 + w) * 8 + lrow;         // 0..63
    int p = rowp[r];
    int pr = (p >= 0) ? p : 0;
    gA[t2] = act + (size_t)pr * I_DIM + jj * 8;
    gB[t2] = wo_e + (size_t)r * I_DIM + jj * 8;
    coff[t2] = (t2 * 4 + w) * 512;
  }

  f32x4 acc[2][2];
#pragma unroll
  for (int i = 0; i < 2; ++i)
#pragma unroll
    for (int j = 0; j < 2; ++j) acc[i][j] = (f32x4){0.f, 0.f, 0.f, 0.f};

  const int msub = (w >> 1) * 32, nsub = (w & 1) * 32;
  const int fm = lane & 15, fq = lane >> 4;

  // prologue: stage tile 0 into buf 0
#pragma unroll
  for (int t2 = 0; t2 < 2; ++t2) {
    gl_lds16(gA[t2], &As[0][coff[t2]]);
    gl_lds16(gB[t2], &Bt[0][coff[t2]]);
  }
  __syncthreads();

  int cur = 0;
  for (int kt = 0; kt < I_DIM; kt += 64) {
    const int nxt = cur ^ 1;
    if (kt + 64 < I_DIM) {
#pragma unroll
      for (int t2 = 0; t2 < 2; ++t2) {
        gl_lds16(gA[t2] + kt + 64, &As[nxt][coff[t2]]);
        gl_lds16(gB[t2] + kt + 64, &Bt[nxt][coff[t2]]);
      }
    }
    const unsigned short* Ac = As[cur];
    const unsigned short* Bc = Bt[cur];
#pragma unroll
    for (int ks = 0; ks < 64; ks += 32) {
      const int cb = (ks >> 3) + fq;
      bf16x8 a[2], b[2];
#pragma unroll
      for (int mi = 0; mi < 2; ++mi)
        a[mi] = FRAG(Ac, msub + mi * 16 + fm, cb);
#pragma unroll
      for (int ni = 0; ni < 2; ++ni)
        b[ni] = FRAG(Bc, nsub + ni * 16 + fm, cb);
#pragma unroll
      for (int mi = 0; mi < 2; ++mi)
#pragma unroll
        for (int ni = 0; ni < 2; ++ni)
          acc[mi][ni] = __builtin_amdgcn_mfma_f32_16x16x32_bf16(a[mi], b[ni], acc[mi][ni], 0, 0, 0);
    }
    __syncthreads();
    cur = nxt;
  }
#pragma unroll
  for (int mi = 0; mi < 2; ++mi) {
#pragma unroll
    for (int r = 0; r < 4; ++r) {
      int ml = msub + mi * 16 + fq * 4 + r;
      int p = rowp[ml];
      if (p < 0) continue;
      float wt = roww[ml];
      float* dst = out + (size_t)(p >> 1) * H_DIM + n0 + nsub + fm;
#pragma unroll
      for (int ni = 0; ni < 2; ++ni)
        atomicAdd(dst + ni * 16, acc[mi][ni][r] * wt);
    }
  }
}

extern "C" void kernel_launch(void* const* d_in, const int* in_sizes, int n_in,
                              void* d_out, int out_size, void* d_ws, size_t ws_size,
                              hipStream_t stream) {
  const float* x   = (const float*)d_in[0];
  const float* wr  = (const float*)d_in[1];
  const float* wi0 = (const float*)d_in[2];
  const float* wi1 = (const float*)d_in[3];
  const float* wo  = (const float*)d_in[4];
  float* out = (float*)d_out;                       // [T,H] f32
  float* logits_out = out + (size_t)T_TOK * H_DIM;  // [T,E] f32

  char* w = (char*)d_ws;
  int* counts    = (int*)w;                                          // 64 B
  int* entries   = (int*)(w + 64);                                   // 128 KB
  float* entry_w = (float*)(w + 64 + (size_t)E_NUM * T_TOK * 4);     // 128 KB
  size_t off = 64 + 2 * (size_t)E_NUM * T_TOK * 4;
  unsigned short* xbf = (unsigned short*)(w + off); off += (size_t)T_TOK * H_DIM * 2;
  unsigned short* wgt = (unsigned short*)(w + off); off += (size_t)E_NUM * H_DIM * I_DIM * 2;
  unsigned short* wut = (unsigned short*)(w + off); off += (size_t)E_NUM * H_DIM * I_DIM * 2;
  unsigned short* wot = (unsigned short*)(w + off); off += (size_t)E_NUM * H_DIM * I_DIM * 2;
  unsigned short* act = (unsigned short*)(w + off);                  // [2T, I] bf16

  hipMemsetAsync(d_out, 0, (size_t)T_TOK * H_DIM * sizeof(float), stream);
  hipMemsetAsync(counts, 0, 64, stream);
  transpose_cast_kernel<<<dim3(I_DIM / 64, H_DIM / 64, E_NUM), 256, 0, stream>>>(
      wi0, wgt, H_DIM, I_DIM);
  transpose_cast_kernel<<<dim3(I_DIM / 64, H_DIM / 64, E_NUM), 256, 0, stream>>>(
      wi1, wut, H_DIM, I_DIM);
  transpose_cast_kernel<<<dim3(H_DIM / 64, I_DIM / 64, E_NUM), 256, 0, stream>>>(
      wo, wot, I_DIM, H_DIM);
  router_kernel<<<T_TOK / RTOK, 256, 0, stream>>>(x, wr, xbf, logits_out, counts, entries, entry_w);
  moe_up_kernel<<<dim3(I_DIM / 64, T_TOK / 64, E_NUM), 256, 0, stream>>>(
      xbf, wgt, wut, counts, entries, act);
  moe_down_kernel<<<dim3(H_DIM / 64, T_TOK / 64, E_NUM), 256, 0, stream>>>(
      act, wot, counts, entries, entry_w, out);
}

// Round 5
// 417.297 us; speedup vs baseline: 1.0787x; 1.0787x over previous
//
#include <hip/hip_runtime.h>

#define T_TOK 4096
#define H_DIM 2048
#define I_DIM 768
#define E_NUM 8

typedef __attribute__((ext_vector_type(8))) short bf16x8;
typedef __attribute__((ext_vector_type(4))) float f32x4;

__device__ __forceinline__ unsigned short f2bf(float f) {
  union { float f; unsigned int u; } c; c.f = f;
  unsigned int r = c.u + 0x7fffu + ((c.u >> 16) & 1u);
  return (unsigned short)(r >> 16);
}

// async global->LDS DMA, 16B per lane; lds dest = wave-uniform base + lane*16
__device__ __forceinline__ void gl_lds16(const unsigned short* g, unsigned short* l) {
  __builtin_amdgcn_global_load_lds(
      (const __attribute__((address_space(1))) unsigned int*)g,
      (__attribute__((address_space(3))) unsigned int*)l, 16, 0, 0);
}

// ---------------- weights: f32 [E][K][N] -> bf16 [E][N][K] ----------------
__global__ __launch_bounds__(256) void transpose_cast_kernel(
    const float* __restrict__ src, unsigned short* __restrict__ dst,
    int K, int N)
{
  const int e = blockIdx.z;
  const int kb = blockIdx.y * 64, nb = blockIdx.x * 64;
  src += (size_t)e * K * N + (size_t)kb * N + nb;
  dst += (size_t)e * N * K + (size_t)nb * K + kb;
  __shared__ float tile[64][65];
  const int tid = threadIdx.x;
  const int lr = tid >> 4, lc = (tid & 15) * 4;
#pragma unroll
  for (int it = 0; it < 4; ++it) {
    float4 v = *(const float4*)(src + (size_t)(lr + it * 16) * N + lc);
    tile[lr + it * 16][lc]     = v.x;
    tile[lr + it * 16][lc + 1] = v.y;
    tile[lr + it * 16][lc + 2] = v.z;
    tile[lr + it * 16][lc + 3] = v.w;
  }
  __syncthreads();
  const int wn = tid >> 2, wk = (tid & 3) * 16;
  union { uint4 u[2]; unsigned short h[16]; } o;
#pragma unroll
  for (int j = 0; j < 16; ++j) o.h[j] = f2bf(tile[wk + j][wn]);
  *(uint4*)(dst + (size_t)wn * K + wk)     = o.u[0];
  *(uint4*)(dst + (size_t)wn * K + wk + 8) = o.u[1];
}

// ---------------- Router (+ fused x f32->bf16 cast) ----------------
// 8 tokens per block, w_router slice cached in registers, block-aggregated
// atomics (<=8 per block instead of 2 dependent per token).
#define RTOK 8
__global__ __launch_bounds__(256) void router_kernel(
    const float* __restrict__ x,               // [T,H] f32
    const float* __restrict__ wr,              // [H,E] f32
    unsigned short* __restrict__ xbf,          // [T,H] bf16 out
    float* __restrict__ logits_out,            // [T,E] f32 (d_out tail)
    int* __restrict__ counts,                  // [E]
    int* __restrict__ entries,                 // [E][T] pair-slot p = t*2+k
    float* __restrict__ entry_w)               // [E][T]
{
  const int tid = threadIdx.x;
  const int w = tid >> 6, lane = tid & 63;
  const int t0 = blockIdx.x * RTOK;
  const int hb = w * 512 + lane * 8;           // this thread's H-chunk base

  // cache this thread's 8 rows x 8 experts of w_router in registers (64 VGPR)
  float wreg[8][8];
#pragma unroll
  for (int r = 0; r < 8; ++r) {
    *(float4*)&wreg[r][0] = *(const float4*)(wr + (size_t)(hb + r) * E_NUM);
    *(float4*)&wreg[r][4] = *(const float4*)(wr + (size_t)(hb + r) * E_NUM + 4);
  }

  __shared__ float red[RTOK][4][E_NUM];        // wave partials
  __shared__ float lg[RTOK][E_NUM];            // logits
  __shared__ int   ch_i[RTOK][2];
  __shared__ float ch_w[RTOK][2];

  for (int tt = 0; tt < RTOK; ++tt) {
    const int t = t0 + tt;
    float xv[8];
    *(float4*)&xv[0] = *(const float4*)(x + (size_t)t * H_DIM + hb);
    *(float4*)&xv[4] = *(const float4*)(x + (size_t)t * H_DIM + hb + 4);
    // fused cast of this x chunk to bf16 (16B/lane, fully coalesced)
    union { uint4 u; unsigned short h[8]; } o;
#pragma unroll
    for (int j = 0; j < 8; ++j) o.h[j] = f2bf(xv[j]);
    *(uint4*)(xbf + (size_t)t * H_DIM + hb) = o.u;

    float acc[E_NUM];
#pragma unroll
    for (int e = 0; e < E_NUM; ++e) acc[e] = 0.f;
#pragma unroll
    for (int r = 0; r < 8; ++r)
#pragma unroll
      for (int e = 0; e < E_NUM; ++e) acc[e] = fmaf(xv[r], wreg[r][e], acc[e]);
#pragma unroll
    for (int off = 32; off > 0; off >>= 1)
#pragma unroll
      for (int e = 0; e < E_NUM; ++e) acc[e] += __shfl_down(acc[e], off);
    if (lane == 0)
#pragma unroll
      for (int e = 0; e < E_NUM; ++e) red[tt][w][e] = acc[e];
  }
  __syncthreads();

  // 64 threads: finish logits (sum 4 wave partials), write logits_out
  if (tid < RTOK * E_NUM) {
    const int tt = tid >> 3, e = tid & 7;
    float l = red[tt][0][e] + red[tt][1][e] + red[tt][2][e] + red[tt][3][e];
    lg[tt][e] = l;
    logits_out[(size_t)(t0 + tt) * E_NUM + e] = l;
  }
  __syncthreads();

  // 8 threads: top-2 per token
  if (tid < RTOK) {
    const int tt = tid;
    float m1 = lg[tt][0]; int i1 = 0;
#pragma unroll
    for (int e = 1; e < E_NUM; ++e) if (lg[tt][e] > m1) { m1 = lg[tt][e]; i1 = e; }
    float m2 = -3.4e38f; int i2 = -1;
#pragma unroll
    for (int e = 0; e < E_NUM; ++e) if (e != i1 && lg[tt][e] > m2) { m2 = lg[tt][e]; i2 = e; }
    float w1 = 1.f / (1.f + __expf(m2 - m1));
    ch_i[tt][0] = i1; ch_i[tt][1] = i2;
    ch_w[tt][0] = w1; ch_w[tt][1] = 1.f - w1;
  }
  __syncthreads();

  // 8 threads (one per expert): aggregate block's pairs, ONE atomic per expert
  if (tid < E_NUM) {
    const int e = tid;
    int cnt = 0;
#pragma unroll
    for (int tt = 0; tt < RTOK; ++tt) {
      if (ch_i[tt][0] == e) ++cnt;
      if (ch_i[tt][1] == e) ++cnt;
    }
    if (cnt > 0) {
      int base = atomicAdd(&counts[e], cnt);
      int pos = 0;
#pragma unroll
      for (int tt = 0; tt < RTOK; ++tt) {
#pragma unroll
        for (int k = 0; k < 2; ++k) {
          if (ch_i[tt][k] == e) {
            entries[e * T_TOK + base + pos] = (t0 + tt) * 2 + k;
            entry_w[e * T_TOK + base + pos] = ch_w[tt][k];
            ++pos;
          }
        }
      }
    }
  }
}

// Fragment read from XOR-swizzled flat tile: row stride 64 shorts, chunk of 8
// physical chunk = logical ^ (row & 7)
#define FRAG(arr, row, cb) \
  (*(const bf16x8*)(&(arr)[((row) << 6) + ((((cb)) ^ ((row) & 7)) << 3)]))

// Map compact linear m-block id -> (expert, m0, cnt). Max m-blocks = 64 + 8.
#define MAX_MB 72

// ---------------- Up-projection: act[p,:] = silu(x Wg) * (x Wu) ----------------
// v5: R1 body (BM=128, BN=64, BK=64, single-buffer, 33KB LDS) + compacted
// 1-D grid: every launched block does work; n innermost (A-tile L2 reuse).
__global__ __launch_bounds__(256) void moe_up_kernel(
    const unsigned short* __restrict__ xbf,   // [T,H] bf16
    const unsigned short* __restrict__ wgt,   // [E][I][H] bf16
    const unsigned short* __restrict__ wut,   // [E][I][H] bf16
    const int* __restrict__ counts,
    const int* __restrict__ entries,
    unsigned short* __restrict__ act)         // [2T, I] bf16
{
  const int bid = blockIdx.x;
  const int nb = bid % (I_DIM / 64);          // 12 n-blocks, innermost
  const int mbl = bid / (I_DIM / 64);
  int e = -1, m0 = 0, cnt = 0, cum = 0;
#pragma unroll
  for (int ee = 0; ee < E_NUM; ++ee) {
    int c = counts[ee];
    int nmb = (c + 127) >> 7;
    if (e < 0 && mbl < cum + nmb) { e = ee; m0 = (mbl - cum) << 7; cnt = c; }
    cum += nmb;
  }
  if (e < 0) return;
  const int n0 = nb * 64;
  const int tid = threadIdx.x;

  __shared__ __align__(16) unsigned short As[128 * 64];
  __shared__ __align__(16) unsigned short Bg[64 * 64];
  __shared__ __align__(16) unsigned short Bu[64 * 64];
  __shared__ int rowp[128];

  if (tid < 128) rowp[tid] = (m0 + tid < cnt) ? entries[e * T_TOK + m0 + tid] : -1;
  __syncthreads();

  const int w = tid >> 6, lane = tid & 63;
  const int lrow = lane >> 3, lchunk = lane & 7;
  const int jj = lchunk ^ lrow;              // swizzled global chunk (lane-const)

  const unsigned short* wg_e = wgt + (size_t)e * I_DIM * H_DIM + (size_t)n0 * H_DIM;
  const unsigned short* wu_e = wut + (size_t)e * I_DIM * H_DIM + (size_t)n0 * H_DIM;
  const unsigned short* gA[4];
  unsigned short* lA[4];
#pragma unroll
  for (int t4 = 0; t4 < 4; ++t4) {
    int r = (t4 * 4 + w) * 8 + lrow;         // 0..127
    int p = rowp[r];
    int tok = (p >= 0) ? (p >> 1) : 0;
    gA[t4] = xbf + (size_t)tok * H_DIM + jj * 8;
    lA[t4] = As + (t4 * 4 + w) * 512;        // 8 rows * 64 shorts
  }
  const unsigned short* gG[2]; const unsigned short* gU[2]; unsigned short* lG[2]; unsigned short* lU[2];
#pragma unroll
  for (int t2 = 0; t2 < 2; ++t2) {
    int r = (t2 * 4 + w) * 8 + lrow;         // 0..63
    gG[t2] = wg_e + (size_t)r * H_DIM + jj * 8;
    gU[t2] = wu_e + (size_t)r * H_DIM + jj * 8;
    lG[t2] = Bg + (t2 * 4 + w) * 512;
    lU[t2] = Bu + (t2 * 4 + w) * 512;
  }

  f32x4 accg[4][2], accu[4][2];
#pragma unroll
  for (int i = 0; i < 4; ++i)
#pragma unroll
    for (int j = 0; j < 2; ++j) {
      accg[i][j] = (f32x4){0.f, 0.f, 0.f, 0.f};
      accu[i][j] = (f32x4){0.f, 0.f, 0.f, 0.f};
    }

  const int msub = (w >> 1) * 64, nsub = (w & 1) * 32;
  const int fm = lane & 15, fq = lane >> 4;

  for (int kt = 0; kt < H_DIM; kt += 64) {
#pragma unroll
    for (int t4 = 0; t4 < 4; ++t4) gl_lds16(gA[t4] + kt, lA[t4]);
#pragma unroll
    for (int t2 = 0; t2 < 2; ++t2) {
      gl_lds16(gG[t2] + kt, lG[t2]);
      gl_lds16(gU[t2] + kt, lU[t2]);
    }
    __syncthreads();
#pragma unroll
    for (int ks = 0; ks < 64; ks += 32) {
      const int cb = (ks >> 3) + fq;
      bf16x8 a[4], bg[2], bu[2];
#pragma unroll
      for (int mi = 0; mi < 4; ++mi)
        a[mi] = FRAG(As, msub + mi * 16 + fm, cb);
#pragma unroll
      for (int ni = 0; ni < 2; ++ni) {
        bg[ni] = FRAG(Bg, nsub + ni * 16 + fm, cb);
        bu[ni] = FRAG(Bu, nsub + ni * 16 + fm, cb);
      }
#pragma unroll
      for (int mi = 0; mi < 4; ++mi)
#pragma unroll
        for (int ni = 0; ni < 2; ++ni) {
          accg[mi][ni] = __builtin_amdgcn_mfma_f32_16x16x32_bf16(a[mi], bg[ni], accg[mi][ni], 0, 0, 0);
          accu[mi][ni] = __builtin_amdgcn_mfma_f32_16x16x32_bf16(a[mi], bu[ni], accu[mi][ni], 0, 0, 0);
        }
    }
    __syncthreads();
  }
#pragma unroll
  for (int mi = 0; mi < 4; ++mi) {
#pragma unroll
    for (int r = 0; r < 4; ++r) {
      int ml = msub + mi * 16 + fq * 4 + r;
      int p = rowp[ml];
      if (p < 0) continue;
      size_t base = (size_t)p * I_DIM + n0 + nsub + fm;
#pragma unroll
      for (int ni = 0; ni < 2; ++ni) {
        float g = accg[mi][ni][r];
        float u = accu[mi][ni][r];
        float h = g / (1.f + __expf(-g)) * u;
        act[base + ni * 16] = f2bf(h);
      }
    }
  }
}

// ---------------- Down-projection + weighted scatter-add into d_out ----------------
// v5: R1 body (BM=128, BN=128, BK=64, single-buffer, 33KB LDS) + compacted grid.
__global__ __launch_bounds__(256) void moe_down_kernel(
    const unsigned short* __restrict__ act,   // [2T, I] bf16
    const unsigned short* __restrict__ wot,   // [E][H][I] bf16
    const int* __restrict__ counts,
    const int* __restrict__ entries,
    const float* __restrict__ entry_w,
    float* __restrict__ out)                  // [T,H] f32
{
  const int bid = blockIdx.x;
  const int nb = bid % (H_DIM / 128);         // 16 n-blocks, innermost
  const int mbl = bid / (H_DIM / 128);
  int e = -1, m0 = 0, cnt = 0, cum = 0;
#pragma unroll
  for (int ee = 0; ee < E_NUM; ++ee) {
    int c = counts[ee];
    int nmb = (c + 127) >> 7;
    if (e < 0 && mbl < cum + nmb) { e = ee; m0 = (mbl - cum) << 7; cnt = c; }
    cum += nmb;
  }
  if (e < 0) return;
  const int n0 = nb * 128;
  const int tid = threadIdx.x;

  __shared__ __align__(16) unsigned short As[128 * 64];
  __shared__ __align__(16) unsigned short Bt[128 * 64];
  __shared__ int rowp[128];
  __shared__ float roww[128];

  if (tid < 128) {
    int idx = m0 + tid;
    rowp[tid] = (idx < cnt) ? entries[e * T_TOK + idx] : -1;
    roww[tid] = (idx < cnt) ? entry_w[e * T_TOK + idx] : 0.f;
  }
  __syncthreads();

  const int w = tid >> 6, lane = tid & 63;
  const int lrow = lane >> 3, lchunk = lane & 7;
  const int jj = lchunk ^ lrow;

  const unsigned short* wo_e = wot + (size_t)e * H_DIM * I_DIM + (size_t)n0 * I_DIM;
  const unsigned short* gA[4]; unsigned short* lA[4];
  const unsigned short* gB[4]; unsigned short* lB[4];
#pragma unroll
  for (int t4 = 0; t4 < 4; ++t4) {
    int r = (t4 * 4 + w) * 8 + lrow;
    int p = rowp[r];
    int pr = (p >= 0) ? p : 0;
    gA[t4] = act + (size_t)pr * I_DIM + jj * 8;
    lA[t4] = As + (t4 * 4 + w) * 512;
    gB[t4] = wo_e + (size_t)r * I_DIM + jj * 8;
    lB[t4] = Bt + (t4 * 4 + w) * 512;
  }

  f32x4 acc[4][4];
#pragma unroll
  for (int i = 0; i < 4; ++i)
#pragma unroll
    for (int j = 0; j < 4; ++j) acc[i][j] = (f32x4){0.f, 0.f, 0.f, 0.f};

  const int msub = (w >> 1) * 64, nsub = (w & 1) * 64;
  const int fm = lane & 15, fq = lane >> 4;

  for (int kt = 0; kt < I_DIM; kt += 64) {
#pragma unroll
    for (int t4 = 0; t4 < 4; ++t4) {
      gl_lds16(gA[t4] + kt, lA[t4]);
      gl_lds16(gB[t4] + kt, lB[t4]);
    }
    __syncthreads();
#pragma unroll
    for (int ks = 0; ks < 64; ks += 32) {
      const int cb = (ks >> 3) + fq;
      bf16x8 a[4], b[4];
#pragma unroll
      for (int mi = 0; mi < 4; ++mi)
        a[mi] = FRAG(As, msub + mi * 16 + fm, cb);
#pragma unroll
      for (int ni = 0; ni < 4; ++ni)
        b[ni] = FRAG(Bt, nsub + ni * 16 + fm, cb);
#pragma unroll
      for (int mi = 0; mi < 4; ++mi)
#pragma unroll
        for (int ni = 0; ni < 4; ++ni)
          acc[mi][ni] = __builtin_amdgcn_mfma_f32_16x16x32_bf16(a[mi], b[ni], acc[mi][ni], 0, 0, 0);
    }
    __syncthreads();
  }
#pragma unroll
  for (int mi = 0; mi < 4; ++mi) {
#pragma unroll
    for (int r = 0; r < 4; ++r) {
      int ml = msub + mi * 16 + fq * 4 + r;
      int p = rowp[ml];
      if (p < 0) continue;
      float wt = roww[ml];
      float* dst = out + (size_t)(p >> 1) * H_DIM + n0 + nsub + fm;
#pragma unroll
      for (int ni = 0; ni < 4; ++ni)
        atomicAdd(dst + ni * 16, acc[mi][ni][r] * wt);
    }
  }
}

extern "C" void kernel_launch(void* const* d_in, const int* in_sizes, int n_in,
                              void* d_out, int out_size, void* d_ws, size_t ws_size,
                              hipStream_t stream) {
  const float* x   = (const float*)d_in[0];
  const float* wr  = (const float*)d_in[1];
  const float* wi0 = (const float*)d_in[2];
  const float* wi1 = (const float*)d_in[3];
  const float* wo  = (const float*)d_in[4];
  float* out = (float*)d_out;                       // [T,H] f32
  float* logits_out = out + (size_t)T_TOK * H_DIM;  // [T,E] f32

  char* w = (char*)d_ws;
  int* counts    = (int*)w;                                          // 64 B
  int* entries   = (int*)(w + 64);                                   // 128 KB
  float* entry_w = (float*)(w + 64 + (size_t)E_NUM * T_TOK * 4);     // 128 KB
  size_t off = 64 + 2 * (size_t)E_NUM * T_TOK * 4;
  unsigned short* xbf = (unsigned short*)(w + off); off += (size_t)T_TOK * H_DIM * 2;
  unsigned short* wgt = (unsigned short*)(w + off); off += (size_t)E_NUM * H_DIM * I_DIM * 2;
  unsigned short* wut = (unsigned short*)(w + off); off += (size_t)E_NUM * H_DIM * I_DIM * 2;
  unsigned short* wot = (unsigned short*)(w + off); off += (size_t)E_NUM * H_DIM * I_DIM * 2;
  unsigned short* act = (unsigned short*)(w + off);                  // [2T, I] bf16

  hipMemsetAsync(d_out, 0, (size_t)T_TOK * H_DIM * sizeof(float), stream);
  hipMemsetAsync(counts, 0, 64, stream);
  transpose_cast_kernel<<<dim3(I_DIM / 64, H_DIM / 64, E_NUM), 256, 0, stream>>>(
      wi0, wgt, H_DIM, I_DIM);
  transpose_cast_kernel<<<dim3(I_DIM / 64, H_DIM / 64, E_NUM), 256, 0, stream>>>(
      wi1, wut, H_DIM, I_DIM);
  transpose_cast_kernel<<<dim3(H_DIM / 64, I_DIM / 64, E_NUM), 256, 0, stream>>>(
      wo, wot, I_DIM, H_DIM);
  router_kernel<<<T_TOK / RTOK, 256, 0, stream>>>(x, wr, xbf, logits_out, counts, entries, entry_w);
  // compacted grids: MAX_MB=72 m-blocks (= 4096*2/128 + 8 ceil slack)
  moe_up_kernel<<<dim3(MAX_MB * (I_DIM / 64)), 256, 0, stream>>>(
      xbf, wgt, wut, counts, entries, act);
  moe_down_kernel<<<dim3(MAX_MB * (H_DIM / 128)), 256, 0, stream>>>(
      act, wot, counts, entries, entry_w, out);
}

// Round 6
// 410.861 us; speedup vs baseline: 1.0956x; 1.0157x over previous
//
#include <hip/hip_runtime.h>

#define T_TOK 4096
#define H_DIM 2048
#define I_DIM 768
#define E_NUM 8

typedef __attribute__((ext_vector_type(8))) short bf16x8;
typedef __attribute__((ext_vector_type(4))) float f32x4;

__device__ __forceinline__ unsigned short f2bf(float f) {
  union { float f; unsigned int u; } c; c.f = f;
  unsigned int r = c.u + 0x7fffu + ((c.u >> 16) & 1u);
  return (unsigned short)(r >> 16);
}

// async global->LDS DMA, 16B per lane; lds dest = wave-uniform base + lane*16
__device__ __forceinline__ void gl_lds16(const unsigned short* g, unsigned short* l) {
  __builtin_amdgcn_global_load_lds(
      (const __attribute__((address_space(1))) unsigned int*)g,
      (__attribute__((address_space(3))) unsigned int*)l, 16, 0, 0);
}

// raw barrier (no vmcnt drain), pinned against compiler memory reordering
__device__ __forceinline__ void barrier_raw() {
  asm volatile("" ::: "memory");
  __builtin_amdgcn_s_barrier();
  asm volatile("" ::: "memory");
}
#define VM_WAIT8 asm volatile("s_waitcnt vmcnt(8)" ::: "memory")
#define VM_WAIT0 asm volatile("s_waitcnt vmcnt(0)" ::: "memory")

// ---------------- weights: f32 [E][K][N] -> bf16 [E][N][K] ----------------
__global__ __launch_bounds__(256) void transpose_cast_kernel(
    const float* __restrict__ src, unsigned short* __restrict__ dst,
    int K, int N)
{
  const int e = blockIdx.z;
  const int kb = blockIdx.y * 64, nb = blockIdx.x * 64;
  src += (size_t)e * K * N + (size_t)kb * N + nb;
  dst += (size_t)e * N * K + (size_t)nb * K + kb;
  __shared__ float tile[64][65];
  const int tid = threadIdx.x;
  const int lr = tid >> 4, lc = (tid & 15) * 4;
#pragma unroll
  for (int it = 0; it < 4; ++it) {
    float4 v = *(const float4*)(src + (size_t)(lr + it * 16) * N + lc);
    tile[lr + it * 16][lc]     = v.x;
    tile[lr + it * 16][lc + 1] = v.y;
    tile[lr + it * 16][lc + 2] = v.z;
    tile[lr + it * 16][lc + 3] = v.w;
  }
  __syncthreads();
  const int wn = tid >> 2, wk = (tid & 3) * 16;
  union { uint4 u[2]; unsigned short h[16]; } o;
#pragma unroll
  for (int j = 0; j < 16; ++j) o.h[j] = f2bf(tile[wk + j][wn]);
  *(uint4*)(dst + (size_t)wn * K + wk)     = o.u[0];
  *(uint4*)(dst + (size_t)wn * K + wk + 8) = o.u[1];
}

// ---------------- Router (+ fused x f32->bf16 cast) ----------------
#define RTOK 8
__global__ __launch_bounds__(256) void router_kernel(
    const float* __restrict__ x,               // [T,H] f32
    const float* __restrict__ wr,              // [H,E] f32
    unsigned short* __restrict__ xbf,          // [T,H] bf16 out
    float* __restrict__ logits_out,            // [T,E] f32 (d_out tail)
    int* __restrict__ counts,                  // [E]
    int* __restrict__ entries,                 // [E][T] pair-slot p = t*2+k
    float* __restrict__ entry_w)               // [E][T]
{
  const int tid = threadIdx.x;
  const int w = tid >> 6, lane = tid & 63;
  const int t0 = blockIdx.x * RTOK;
  const int hb = w * 512 + lane * 8;           // this thread's H-chunk base

  float wreg[8][8];
#pragma unroll
  for (int r = 0; r < 8; ++r) {
    *(float4*)&wreg[r][0] = *(const float4*)(wr + (size_t)(hb + r) * E_NUM);
    *(float4*)&wreg[r][4] = *(const float4*)(wr + (size_t)(hb + r) * E_NUM + 4);
  }

  __shared__ float red[RTOK][4][E_NUM];        // wave partials
  __shared__ float lg[RTOK][E_NUM];            // logits
  __shared__ int   ch_i[RTOK][2];
  __shared__ float ch_w[RTOK][2];

  for (int tt = 0; tt < RTOK; ++tt) {
    const int t = t0 + tt;
    float xv[8];
    *(float4*)&xv[0] = *(const float4*)(x + (size_t)t * H_DIM + hb);
    *(float4*)&xv[4] = *(const float4*)(x + (size_t)t * H_DIM + hb + 4);
    union { uint4 u; unsigned short h[8]; } o;
#pragma unroll
    for (int j = 0; j < 8; ++j) o.h[j] = f2bf(xv[j]);
    *(uint4*)(xbf + (size_t)t * H_DIM + hb) = o.u;

    float acc[E_NUM];
#pragma unroll
    for (int e = 0; e < E_NUM; ++e) acc[e] = 0.f;
#pragma unroll
    for (int r = 0; r < 8; ++r)
#pragma unroll
      for (int e = 0; e < E_NUM; ++e) acc[e] = fmaf(xv[r], wreg[r][e], acc[e]);
#pragma unroll
    for (int off = 32; off > 0; off >>= 1)
#pragma unroll
      for (int e = 0; e < E_NUM; ++e) acc[e] += __shfl_down(acc[e], off);
    if (lane == 0)
#pragma unroll
      for (int e = 0; e < E_NUM; ++e) red[tt][w][e] = acc[e];
  }
  __syncthreads();

  if (tid < RTOK * E_NUM) {
    const int tt = tid >> 3, e = tid & 7;
    float l = red[tt][0][e] + red[tt][1][e] + red[tt][2][e] + red[tt][3][e];
    lg[tt][e] = l;
    logits_out[(size_t)(t0 + tt) * E_NUM + e] = l;
  }
  __syncthreads();

  if (tid < RTOK) {
    const int tt = tid;
    float m1 = lg[tt][0]; int i1 = 0;
#pragma unroll
    for (int e = 1; e < E_NUM; ++e) if (lg[tt][e] > m1) { m1 = lg[tt][e]; i1 = e; }
    float m2 = -3.4e38f; int i2 = -1;
#pragma unroll
    for (int e = 0; e < E_NUM; ++e) if (e != i1 && lg[tt][e] > m2) { m2 = lg[tt][e]; i2 = e; }
    float w1 = 1.f / (1.f + __expf(m2 - m1));
    ch_i[tt][0] = i1; ch_i[tt][1] = i2;
    ch_w[tt][0] = w1; ch_w[tt][1] = 1.f - w1;
  }
  __syncthreads();

  if (tid < E_NUM) {
    const int e = tid;
    int cnt = 0;
#pragma unroll
    for (int tt = 0; tt < RTOK; ++tt) {
      if (ch_i[tt][0] == e) ++cnt;
      if (ch_i[tt][1] == e) ++cnt;
    }
    if (cnt > 0) {
      int base = atomicAdd(&counts[e], cnt);
      int pos = 0;
#pragma unroll
      for (int tt = 0; tt < RTOK; ++tt) {
#pragma unroll
        for (int k = 0; k < 2; ++k) {
          if (ch_i[tt][k] == e) {
            entries[e * T_TOK + base + pos] = (t0 + tt) * 2 + k;
            entry_w[e * T_TOK + base + pos] = ch_w[tt][k];
            ++pos;
          }
        }
      }
    }
  }
}

// Fragment read from XOR-swizzled flat tile: row stride 64 shorts, chunk of 8
// physical chunk = logical ^ (row & 7)
#define FRAG(arr, row, cb) \
  (*(const bf16x8*)(&(arr)[((row) << 6) + ((((cb)) ^ ((row) & 7)) << 3)]))

#define MAX_MB 72

// ---------------- Up-projection: act[p,:] = silu(x Wg) * (x Wu) ----------------
// v6: BM=128 BN=64 BK=64, double-buffered, 2-deep COUNTED-vmcnt pipeline
// (T3+T4): per K-step issue tile t+2's 8 loads, wait vmcnt(8) (t+1 landed,
// t+2 in flight), raw barrier — no vmcnt(0) drain in the loop. + T5 setprio.
__global__ __launch_bounds__(256) void moe_up_kernel(
    const unsigned short* __restrict__ xbf,   // [T,H] bf16
    const unsigned short* __restrict__ wgt,   // [E][I][H] bf16
    const unsigned short* __restrict__ wut,   // [E][I][H] bf16
    const int* __restrict__ counts,
    const int* __restrict__ entries,
    unsigned short* __restrict__ act)         // [2T, I] bf16
{
  const int bid = blockIdx.x;
  const int nb = bid % (I_DIM / 64);          // 12 n-blocks, innermost
  const int mbl = bid / (I_DIM / 64);
  int e = -1, m0 = 0, cnt = 0, cum = 0;
#pragma unroll
  for (int ee = 0; ee < E_NUM; ++ee) {
    int c = counts[ee];
    int nmb = (c + 127) >> 7;
    if (e < 0 && mbl < cum + nmb) { e = ee; m0 = (mbl - cum) << 7; cnt = c; }
    cum += nmb;
  }
  if (e < 0) return;
  const int n0 = nb * 64;
  const int tid = threadIdx.x;

  __shared__ __align__(16) unsigned short As[2][128 * 64];
  __shared__ __align__(16) unsigned short Bg[2][64 * 64];
  __shared__ __align__(16) unsigned short Bu[2][64 * 64];
  __shared__ int rowp[128];

  if (tid < 128) rowp[tid] = (m0 + tid < cnt) ? entries[e * T_TOK + m0 + tid] : -1;
  __syncthreads();

  const int w = tid >> 6, lane = tid & 63;
  const int lrow = lane >> 3, lchunk = lane & 7;
  const int jj = lchunk ^ lrow;              // swizzled global chunk (lane-const)

  const unsigned short* wg_e = wgt + (size_t)e * I_DIM * H_DIM + (size_t)n0 * H_DIM;
  const unsigned short* wu_e = wut + (size_t)e * I_DIM * H_DIM + (size_t)n0 * H_DIM;
  const unsigned short* gA[4];
  int aoff[4];
#pragma unroll
  for (int t4 = 0; t4 < 4; ++t4) {
    int r = (t4 * 4 + w) * 8 + lrow;         // 0..127
    int p = rowp[r];
    int tok = (p >= 0) ? (p >> 1) : 0;
    gA[t4] = xbf + (size_t)tok * H_DIM + jj * 8;
    aoff[t4] = (t4 * 4 + w) * 512;           // 8 rows * 64 shorts
  }
  const unsigned short* gG[2]; const unsigned short* gU[2];
  int boff[2];
#pragma unroll
  for (int t2 = 0; t2 < 2; ++t2) {
    int r = (t2 * 4 + w) * 8 + lrow;         // 0..63
    gG[t2] = wg_e + (size_t)r * H_DIM + jj * 8;
    gU[t2] = wu_e + (size_t)r * H_DIM + jj * 8;
    boff[t2] = (t2 * 4 + w) * 512;
  }

  f32x4 accg[4][2], accu[4][2];
#pragma unroll
  for (int i = 0; i < 4; ++i)
#pragma unroll
    for (int j = 0; j < 2; ++j) {
      accg[i][j] = (f32x4){0.f, 0.f, 0.f, 0.f};
      accu[i][j] = (f32x4){0.f, 0.f, 0.f, 0.f};
    }

  const int msub = (w >> 1) * 64, nsub = (w & 1) * 32;
  const int fm = lane & 15, fq = lane >> 4;

  auto stage = [&](int kt, int b) {          // 8 loads per thread
#pragma unroll
    for (int t4 = 0; t4 < 4; ++t4) gl_lds16(gA[t4] + kt, &As[b][aoff[t4]]);
#pragma unroll
    for (int t2 = 0; t2 < 2; ++t2) {
      gl_lds16(gG[t2] + kt, &Bg[b][boff[t2]]);
      gl_lds16(gU[t2] + kt, &Bu[b][boff[t2]]);
    }
  };

  // prologue: tiles 0 and 1 in flight; wait tile 0 only
  stage(0, 0);
  stage(64, 1);
  VM_WAIT8;
  barrier_raw();

  int cur = 0;
  const int NT = H_DIM / 64;                 // 32
  for (int t = 0; t < NT; ++t) {
    const unsigned short* Ac  = As[cur];
    const unsigned short* Bgc = Bg[cur];
    const unsigned short* Buc = Bu[cur];
#pragma unroll
    for (int ks = 0; ks < 64; ks += 32) {
      const int cb = (ks >> 3) + fq;
      bf16x8 a[4], bg[2], bu[2];
#pragma unroll
      for (int mi = 0; mi < 4; ++mi)
        a[mi] = FRAG(Ac, msub + mi * 16 + fm, cb);
#pragma unroll
      for (int ni = 0; ni < 2; ++ni) {
        bg[ni] = FRAG(Bgc, nsub + ni * 16 + fm, cb);
        bu[ni] = FRAG(Buc, nsub + ni * 16 + fm, cb);
      }
      __builtin_amdgcn_s_setprio(1);
#pragma unroll
      for (int mi = 0; mi < 4; ++mi)
#pragma unroll
        for (int ni = 0; ni < 2; ++ni) {
          accg[mi][ni] = __builtin_amdgcn_mfma_f32_16x16x32_bf16(a[mi], bg[ni], accg[mi][ni], 0, 0, 0);
          accu[mi][ni] = __builtin_amdgcn_mfma_f32_16x16x32_bf16(a[mi], bu[ni], accu[mi][ni], 0, 0, 0);
        }
      __builtin_amdgcn_s_setprio(0);
    }
    barrier_raw();                           // all waves done reading buf[cur]
    if (t + 2 < NT) {
      stage((t + 2) * 64, cur);              // refill the buffer just freed
      VM_WAIT8;                              // tile t+1 landed; t+2 in flight
    } else {
      VM_WAIT0;                              // tail: drain once
    }
    barrier_raw();                           // t+1 visible to all waves
    cur ^= 1;
  }

#pragma unroll
  for (int mi = 0; mi < 4; ++mi) {
#pragma unroll
    for (int r = 0; r < 4; ++r) {
      int ml = msub + mi * 16 + fq * 4 + r;
      int p = rowp[ml];
      if (p < 0) continue;
      size_t base = (size_t)p * I_DIM + n0 + nsub + fm;
#pragma unroll
      for (int ni = 0; ni < 2; ++ni) {
        float g = accg[mi][ni][r];
        float u = accu[mi][ni][r];
        float h = g / (1.f + __expf(-g)) * u;
        act[base + ni * 16] = f2bf(h);
      }
    }
  }
}

// ---------------- Down-projection + weighted scatter-add into d_out ----------------
// v6: BM=128 BN=128 BK=64, double-buffered, 2-deep counted-vmcnt pipeline.
__global__ __launch_bounds__(256) void moe_down_kernel(
    const unsigned short* __restrict__ act,   // [2T, I] bf16
    const unsigned short* __restrict__ wot,   // [E][H][I] bf16
    const int* __restrict__ counts,
    const int* __restrict__ entries,
    const float* __restrict__ entry_w,
    float* __restrict__ out)                  // [T,H] f32
{
  const int bid = blockIdx.x;
  const int nb = bid % (H_DIM / 128);         // 16 n-blocks, innermost
  const int mbl = bid / (H_DIM / 128);
  int e = -1, m0 = 0, cnt = 0, cum = 0;
#pragma unroll
  for (int ee = 0; ee < E_NUM; ++ee) {
    int c = counts[ee];
    int nmb = (c + 127) >> 7;
    if (e < 0 && mbl < cum + nmb) { e = ee; m0 = (mbl - cum) << 7; cnt = c; }
    cum += nmb;
  }
  if (e < 0) return;
  const int n0 = nb * 128;
  const int tid = threadIdx.x;

  __shared__ __align__(16) unsigned short As[2][128 * 64];
  __shared__ __align__(16) unsigned short Bt[2][128 * 64];
  __shared__ int rowp[128];
  __shared__ float roww[128];

  if (tid < 128) {
    int idx = m0 + tid;
    rowp[tid] = (idx < cnt) ? entries[e * T_TOK + idx] : -1;
    roww[tid] = (idx < cnt) ? entry_w[e * T_TOK + idx] : 0.f;
  }
  __syncthreads();

  const int w = tid >> 6, lane = tid & 63;
  const int lrow = lane >> 3, lchunk = lane & 7;
  const int jj = lchunk ^ lrow;

  const unsigned short* wo_e = wot + (size_t)e * H_DIM * I_DIM + (size_t)n0 * I_DIM;
  const unsigned short* gA[4]; const unsigned short* gB[4];
  int coff[4];
#pragma unroll
  for (int t4 = 0; t4 < 4; ++t4) {
    int r = (t4 * 4 + w) * 8 + lrow;
    int p = rowp[r];
    int pr = (p >= 0) ? p : 0;
    gA[t4] = act + (size_t)pr * I_DIM + jj * 8;
    gB[t4] = wo_e + (size_t)r * I_DIM + jj * 8;
    coff[t4] = (t4 * 4 + w) * 512;
  }

  f32x4 acc[4][4];
#pragma unroll
  for (int i = 0; i < 4; ++i)
#pragma unroll
    for (int j = 0; j < 4; ++j) acc[i][j] = (f32x4){0.f, 0.f, 0.f, 0.f};

  const int msub = (w >> 1) * 64, nsub = (w & 1) * 64;
  const int fm = lane & 15, fq = lane >> 4;

  auto stage = [&](int kt, int b) {          // 8 loads per thread
#pragma unroll
    for (int t4 = 0; t4 < 4; ++t4) {
      gl_lds16(gA[t4] + kt, &As[b][coff[t4]]);
      gl_lds16(gB[t4] + kt, &Bt[b][coff[t4]]);
    }
  };

  stage(0, 0);
  stage(64, 1);
  VM_WAIT8;
  barrier_raw();

  int cur = 0;
  const int NT = I_DIM / 64;                 // 12
  for (int t = 0; t < NT; ++t) {
    const unsigned short* Ac = As[cur];
    const unsigned short* Bc = Bt[cur];
#pragma unroll
    for (int ks = 0; ks < 64; ks += 32) {
      const int cb = (ks >> 3) + fq;
      bf16x8 a[4], b[4];
#pragma unroll
      for (int mi = 0; mi < 4; ++mi)
        a[mi] = FRAG(Ac, msub + mi * 16 + fm, cb);
#pragma unroll
      for (int ni = 0; ni < 4; ++ni)
        b[ni] = FRAG(Bc, nsub + ni * 16 + fm, cb);
      __builtin_amdgcn_s_setprio(1);
#pragma unroll
      for (int mi = 0; mi < 4; ++mi)
#pragma unroll
        for (int ni = 0; ni < 4; ++ni)
          acc[mi][ni] = __builtin_amdgcn_mfma_f32_16x16x32_bf16(a[mi], b[ni], acc[mi][ni], 0, 0, 0);
      __builtin_amdgcn_s_setprio(0);
    }
    barrier_raw();
    if (t + 2 < NT) {
      stage((t + 2) * 64, cur);
      VM_WAIT8;
    } else {
      VM_WAIT0;
    }
    barrier_raw();
    cur ^= 1;
  }

#pragma unroll
  for (int mi = 0; mi < 4; ++mi) {
#pragma unroll
    for (int r = 0; r < 4; ++r) {
      int ml = msub + mi * 16 + fq * 4 + r;
      int p = rowp[ml];
      if (p < 0) continue;
      float wt = roww[ml];
      float* dst = out + (size_t)(p >> 1) * H_DIM + n0 + nsub + fm;
#pragma unroll
      for (int ni = 0; ni < 4; ++ni)
        atomicAdd(dst + ni * 16, acc[mi][ni][r] * wt);
    }
  }
}

extern "C" void kernel_launch(void* const* d_in, const int* in_sizes, int n_in,
                              void* d_out, int out_size, void* d_ws, size_t ws_size,
                              hipStream_t stream) {
  const float* x   = (const float*)d_in[0];
  const float* wr  = (const float*)d_in[1];
  const float* wi0 = (const float*)d_in[2];
  const float* wi1 = (const float*)d_in[3];
  const float* wo  = (const float*)d_in[4];
  float* out = (float*)d_out;                       // [T,H] f32
  float* logits_out = out + (size_t)T_TOK * H_DIM;  // [T,E] f32

  char* w = (char*)d_ws;
  int* counts    = (int*)w;                                          // 64 B
  int* entries   = (int*)(w + 64);                                   // 128 KB
  float* entry_w = (float*)(w + 64 + (size_t)E_NUM * T_TOK * 4);     // 128 KB
  size_t off = 64 + 2 * (size_t)E_NUM * T_TOK * 4;
  unsigned short* xbf = (unsigned short*)(w + off); off += (size_t)T_TOK * H_DIM * 2;
  unsigned short* wgt = (unsigned short*)(w + off); off += (size_t)E_NUM * H_DIM * I_DIM * 2;
  unsigned short* wut = (unsigned short*)(w + off); off += (size_t)E_NUM * H_DIM * I_DIM * 2;
  unsigned short* wot = (unsigned short*)(w + off); off += (size_t)E_NUM * H_DIM * I_DIM * 2;
  unsigned short* act = (unsigned short*)(w + off);                  // [2T, I] bf16

  hipMemsetAsync(d_out, 0, (size_t)T_TOK * H_DIM * sizeof(float), stream);
  hipMemsetAsync(counts, 0, 64, stream);
  transpose_cast_kernel<<<dim3(I_DIM / 64, H_DIM / 64, E_NUM), 256, 0, stream>>>(
      wi0, wgt, H_DIM, I_DIM);
  transpose_cast_kernel<<<dim3(I_DIM / 64, H_DIM / 64, E_NUM), 256, 0, stream>>>(
      wi1, wut, H_DIM, I_DIM);
  transpose_cast_kernel<<<dim3(H_DIM / 64, I_DIM / 64, E_NUM), 256, 0, stream>>>(
      wo, wot, I_DIM, H_DIM);
  router_kernel<<<T_TOK / RTOK, 256, 0, stream>>>(x, wr, xbf, logits_out, counts, entries, entry_w);
  // compacted grids: MAX_MB=72 m-blocks (= 4096*2/128 + 8 ceil slack)
  moe_up_kernel<<<dim3(MAX_MB * (I_DIM / 64)), 256, 0, stream>>>(
      xbf, wgt, wut, counts, entries, act);
  moe_down_kernel<<<dim3(MAX_MB * (H_DIM / 128)), 256, 0, stream>>>(
      act, wot, counts, entries, entry_w, out);
}

// Round 7
// 410.429 us; speedup vs baseline: 1.0967x; 1.0011x over previous
//
#include <hip/hip_runtime.h>

#define T_TOK 4096
#define H_DIM 2048
#define I_DIM 768
#define E_NUM 8

typedef __attribute__((ext_vector_type(8))) short bf16x8;
typedef __attribute__((ext_vector_type(4))) float f32x4;

__device__ __forceinline__ unsigned short f2bf(float f) {
  union { float f; unsigned int u; } c; c.f = f;
  unsigned int r = c.u + 0x7fffu + ((c.u >> 16) & 1u);
  return (unsigned short)(r >> 16);
}

// async global->LDS DMA, 16B per lane; lds dest = wave-uniform base + lane*16
__device__ __forceinline__ void gl_lds16(const unsigned short* g, unsigned short* l) {
  __builtin_amdgcn_global_load_lds(
      (const __attribute__((address_space(1))) unsigned int*)g,
      (__attribute__((address_space(3))) unsigned int*)l, 16, 0, 0);
}

#define RTOK 8
// prep job ranges (block-uniform branches)
#define PREP_T0 3072              // wi0 -> wgt
#define PREP_T1 6144              // wi1 -> wut
#define PREP_T2 9216              // wo  -> wot
#define PREP_TOTAL (PREP_T2 + T_TOK / RTOK)   // + router

struct RouterSmem {
  float red[RTOK][4][E_NUM];
  float lg[RTOK][E_NUM];
  int   ch_i[RTOK][2];
  float ch_w[RTOK][2];
};

// ---------------- merged prep: 3 weight transposes + router ----------------
__global__ __launch_bounds__(256) void prep_kernel(
    const float* __restrict__ wi0, const float* __restrict__ wi1,
    const float* __restrict__ wo,
    unsigned short* __restrict__ wgt, unsigned short* __restrict__ wut,
    unsigned short* __restrict__ wot,
    const float* __restrict__ x, const float* __restrict__ wr,
    unsigned short* __restrict__ xbf, float* __restrict__ logits_out,
    int* __restrict__ counts, int* __restrict__ entries,
    float* __restrict__ entry_w)
{
  __shared__ __align__(16) char smem[64 * 65 * 4];
  const int bid = blockIdx.x;
  const int tid = threadIdx.x;

  if (bid < PREP_T2) {
    // ---- transpose job: f32 [E][K][N] -> bf16 [E][N][K] ----
    const float* src; unsigned short* dst; int K, N, lb;
    if (bid < PREP_T0)      { src = wi0; dst = wgt; K = H_DIM; N = I_DIM; lb = bid; }
    else if (bid < PREP_T1) { src = wi1; dst = wut; K = H_DIM; N = I_DIM; lb = bid - PREP_T0; }
    else                    { src = wo;  dst = wot; K = I_DIM; N = H_DIM; lb = bid - PREP_T1; }
    const int nx = N / 64, ky = K / 64;
    const int nb = (lb % nx) * 64;
    const int kb = ((lb / nx) % ky) * 64;
    const int e  = lb / (nx * ky);
    src += (size_t)e * K * N + (size_t)kb * N + nb;
    dst += (size_t)e * N * K + (size_t)nb * K + kb;
    float (*tile)[65] = (float(*)[65])smem;
    const int lr = tid >> 4, lc = (tid & 15) * 4;
#pragma unroll
    for (int it = 0; it < 4; ++it) {
      float4 v = *(const float4*)(src + (size_t)(lr + it * 16) * N + lc);
      tile[lr + it * 16][lc]     = v.x;
      tile[lr + it * 16][lc + 1] = v.y;
      tile[lr + it * 16][lc + 2] = v.z;
      tile[lr + it * 16][lc + 3] = v.w;
    }
    __syncthreads();
    const int wn = tid >> 2, wk = (tid & 3) * 16;
    union { uint4 u[2]; unsigned short h[16]; } o;
#pragma unroll
    for (int j = 0; j < 16; ++j) o.h[j] = f2bf(tile[wk + j][wn]);
    *(uint4*)(dst + (size_t)wn * K + wk)     = o.u[0];
    *(uint4*)(dst + (size_t)wn * K + wk + 8) = o.u[1];
    return;
  }

  // ---- router job (+ fused x f32->bf16 cast) ----
  RouterSmem* rs = (RouterSmem*)smem;
  const int w = tid >> 6, lane = tid & 63;
  const int t0 = (bid - PREP_T2) * RTOK;
  const int hb = w * 512 + lane * 8;

  float wreg[8][8];
#pragma unroll
  for (int r = 0; r < 8; ++r) {
    *(float4*)&wreg[r][0] = *(const float4*)(wr + (size_t)(hb + r) * E_NUM);
    *(float4*)&wreg[r][4] = *(const float4*)(wr + (size_t)(hb + r) * E_NUM + 4);
  }

  for (int tt = 0; tt < RTOK; ++tt) {
    const int t = t0 + tt;
    float xv[8];
    *(float4*)&xv[0] = *(const float4*)(x + (size_t)t * H_DIM + hb);
    *(float4*)&xv[4] = *(const float4*)(x + (size_t)t * H_DIM + hb + 4);
    union { uint4 u; unsigned short h[8]; } o;
#pragma unroll
    for (int j = 0; j < 8; ++j) o.h[j] = f2bf(xv[j]);
    *(uint4*)(xbf + (size_t)t * H_DIM + hb) = o.u;

    float acc[E_NUM];
#pragma unroll
    for (int e = 0; e < E_NUM; ++e) acc[e] = 0.f;
#pragma unroll
    for (int r = 0; r < 8; ++r)
#pragma unroll
      for (int e = 0; e < E_NUM; ++e) acc[e] = fmaf(xv[r], wreg[r][e], acc[e]);
#pragma unroll
    for (int off = 32; off > 0; off >>= 1)
#pragma unroll
      for (int e = 0; e < E_NUM; ++e) acc[e] += __shfl_down(acc[e], off);
    if (lane == 0)
#pragma unroll
      for (int e = 0; e < E_NUM; ++e) rs->red[tt][w][e] = acc[e];
  }
  __syncthreads();

  if (tid < RTOK * E_NUM) {
    const int tt = tid >> 3, e = tid & 7;
    float l = rs->red[tt][0][e] + rs->red[tt][1][e] + rs->red[tt][2][e] + rs->red[tt][3][e];
    rs->lg[tt][e] = l;
    logits_out[(size_t)(t0 + tt) * E_NUM + e] = l;
  }
  __syncthreads();

  if (tid < RTOK) {
    const int tt = tid;
    float m1 = rs->lg[tt][0]; int i1 = 0;
#pragma unroll
    for (int e = 1; e < E_NUM; ++e) if (rs->lg[tt][e] > m1) { m1 = rs->lg[tt][e]; i1 = e; }
    float m2 = -3.4e38f; int i2 = -1;
#pragma unroll
    for (int e = 0; e < E_NUM; ++e) if (e != i1 && rs->lg[tt][e] > m2) { m2 = rs->lg[tt][e]; i2 = e; }
    float w1 = 1.f / (1.f + __expf(m2 - m1));
    rs->ch_i[tt][0] = i1; rs->ch_i[tt][1] = i2;
    rs->ch_w[tt][0] = w1; rs->ch_w[tt][1] = 1.f - w1;
  }
  __syncthreads();

  if (tid < E_NUM) {
    const int e = tid;
    int cnt = 0;
#pragma unroll
    for (int tt = 0; tt < RTOK; ++tt) {
      if (rs->ch_i[tt][0] == e) ++cnt;
      if (rs->ch_i[tt][1] == e) ++cnt;
    }
    if (cnt > 0) {
      int base = atomicAdd(&counts[e], cnt);
      int pos = 0;
#pragma unroll
      for (int tt = 0; tt < RTOK; ++tt) {
#pragma unroll
        for (int k = 0; k < 2; ++k) {
          if (rs->ch_i[tt][k] == e) {
            entries[e * T_TOK + base + pos] = (t0 + tt) * 2 + k;
            entry_w[e * T_TOK + base + pos] = rs->ch_w[tt][k];
            ++pos;
          }
        }
      }
    }
  }
}

// Fragment read from XOR-swizzled flat tile: row stride 64 shorts, chunk of 8
// physical chunk = logical ^ (row & 7)
#define FRAG(arr, row, cb) \
  (*(const bf16x8*)(&(arr)[((row) << 6) + ((((cb)) ^ ((row) & 7)) << 3)]))

#define MAX_MB 72
#define UP_NB (I_DIM / 64)        // 12 -> grid 864 = 8 * 108
#define DN_NB (H_DIM / 128)       // 16 -> grid 1152 = 8 * 144

// ---------------- Up-projection: act[p,:] = silu(x Wg) * (x Wu) ----------------
// v7: R5 body (BM=128 BN=64 BK=64, single-buffer, 33KB LDS, compacted grid)
// + T1 XCD-chunked swizzle: each XCD owns a contiguous 108-block run, so
// A-panels (12 consecutive n-blocks) and weight panels (stride-12 m-blocks)
// stay in ONE per-XCD L2 -> HBM fetch and drain latency drop.
__global__ __launch_bounds__(256) void moe_up_kernel(
    const unsigned short* __restrict__ xbf,   // [T,H] bf16
    const unsigned short* __restrict__ wgt,   // [E][I][H] bf16
    const unsigned short* __restrict__ wut,   // [E][I][H] bf16
    const int* __restrict__ counts,
    const int* __restrict__ entries,
    unsigned short* __restrict__ act)         // [2T, I] bf16
{
  // XCD swizzle (bijective: 864 % 8 == 0)
  const int sb = (blockIdx.x & 7) * (MAX_MB * UP_NB / 8) + (blockIdx.x >> 3);
  const int nb = sb % UP_NB;                  // n innermost within chunk
  const int mbl = sb / UP_NB;
  int e = -1, m0 = 0, cnt = 0, cum = 0;
#pragma unroll
  for (int ee = 0; ee < E_NUM; ++ee) {
    int c = counts[ee];
    int nmb = (c + 127) >> 7;
    if (e < 0 && mbl < cum + nmb) { e = ee; m0 = (mbl - cum) << 7; cnt = c; }
    cum += nmb;
  }
  if (e < 0) return;
  const int n0 = nb * 64;
  const int tid = threadIdx.x;

  __shared__ __align__(16) unsigned short As[128 * 64];
  __shared__ __align__(16) unsigned short Bg[64 * 64];
  __shared__ __align__(16) unsigned short Bu[64 * 64];
  __shared__ int rowp[128];

  if (tid < 128) rowp[tid] = (m0 + tid < cnt) ? entries[e * T_TOK + m0 + tid] : -1;
  __syncthreads();

  const int w = tid >> 6, lane = tid & 63;
  const int lrow = lane >> 3, lchunk = lane & 7;
  const int jj = lchunk ^ lrow;              // swizzled global chunk (lane-const)

  const unsigned short* wg_e = wgt + (size_t)e * I_DIM * H_DIM + (size_t)n0 * H_DIM;
  const unsigned short* wu_e = wut + (size_t)e * I_DIM * H_DIM + (size_t)n0 * H_DIM;
  const unsigned short* gA[4];
  unsigned short* lA[4];
#pragma unroll
  for (int t4 = 0; t4 < 4; ++t4) {
    int r = (t4 * 4 + w) * 8 + lrow;         // 0..127
    int p = rowp[r];
    int tok = (p >= 0) ? (p >> 1) : 0;
    gA[t4] = xbf + (size_t)tok * H_DIM + jj * 8;
    lA[t4] = As + (t4 * 4 + w) * 512;        // 8 rows * 64 shorts
  }
  const unsigned short* gG[2]; const unsigned short* gU[2]; unsigned short* lG[2]; unsigned short* lU[2];
#pragma unroll
  for (int t2 = 0; t2 < 2; ++t2) {
    int r = (t2 * 4 + w) * 8 + lrow;         // 0..63
    gG[t2] = wg_e + (size_t)r * H_DIM + jj * 8;
    gU[t2] = wu_e + (size_t)r * H_DIM + jj * 8;
    lG[t2] = Bg + (t2 * 4 + w) * 512;
    lU[t2] = Bu + (t2 * 4 + w) * 512;
  }

  f32x4 accg[4][2], accu[4][2];
#pragma unroll
  for (int i = 0; i < 4; ++i)
#pragma unroll
    for (int j = 0; j < 2; ++j) {
      accg[i][j] = (f32x4){0.f, 0.f, 0.f, 0.f};
      accu[i][j] = (f32x4){0.f, 0.f, 0.f, 0.f};
    }

  const int msub = (w >> 1) * 64, nsub = (w & 1) * 32;
  const int fm = lane & 15, fq = lane >> 4;

  for (int kt = 0; kt < H_DIM; kt += 64) {
#pragma unroll
    for (int t4 = 0; t4 < 4; ++t4) gl_lds16(gA[t4] + kt, lA[t4]);
#pragma unroll
    for (int t2 = 0; t2 < 2; ++t2) {
      gl_lds16(gG[t2] + kt, lG[t2]);
      gl_lds16(gU[t2] + kt, lU[t2]);
    }
    __syncthreads();
#pragma unroll
    for (int ks = 0; ks < 64; ks += 32) {
      const int cb = (ks >> 3) + fq;
      bf16x8 a[4], bg[2], bu[2];
#pragma unroll
      for (int mi = 0; mi < 4; ++mi)
        a[mi] = FRAG(As, msub + mi * 16 + fm, cb);
#pragma unroll
      for (int ni = 0; ni < 2; ++ni) {
        bg[ni] = FRAG(Bg, nsub + ni * 16 + fm, cb);
        bu[ni] = FRAG(Bu, nsub + ni * 16 + fm, cb);
      }
#pragma unroll
      for (int mi = 0; mi < 4; ++mi)
#pragma unroll
        for (int ni = 0; ni < 2; ++ni) {
          accg[mi][ni] = __builtin_amdgcn_mfma_f32_16x16x32_bf16(a[mi], bg[ni], accg[mi][ni], 0, 0, 0);
          accu[mi][ni] = __builtin_amdgcn_mfma_f32_16x16x32_bf16(a[mi], bu[ni], accu[mi][ni], 0, 0, 0);
        }
    }
    __syncthreads();
  }
#pragma unroll
  for (int mi = 0; mi < 4; ++mi) {
#pragma unroll
    for (int r = 0; r < 4; ++r) {
      int ml = msub + mi * 16 + fq * 4 + r;
      int p = rowp[ml];
      if (p < 0) continue;
      size_t base = (size_t)p * I_DIM + n0 + nsub + fm;
#pragma unroll
      for (int ni = 0; ni < 2; ++ni) {
        float g = accg[mi][ni][r];
        float u = accu[mi][ni][r];
        float h = g / (1.f + __expf(-g)) * u;
        act[base + ni * 16] = f2bf(h);
      }
    }
  }
}

// ---------------- Down-projection + weighted scatter-add into d_out ----------------
// v7: R5 body (BM=128 BN=128 BK=64, single-buffer) + T1 XCD-chunked swizzle.
__global__ __launch_bounds__(256) void moe_down_kernel(
    const unsigned short* __restrict__ act,   // [2T, I] bf16
    const unsigned short* __restrict__ wot,   // [E][H][I] bf16
    const int* __restrict__ counts,
    const int* __restrict__ entries,
    const float* __restrict__ entry_w,
    float* __restrict__ out)                  // [T,H] f32
{
  // XCD swizzle (bijective: 1152 % 8 == 0)
  const int sb = (blockIdx.x & 7) * (MAX_MB * DN_NB / 8) + (blockIdx.x >> 3);
  const int nb = sb % DN_NB;                  // 16 n-blocks, innermost
  const int mbl = sb / DN_NB;
  int e = -1, m0 = 0, cnt = 0, cum = 0;
#pragma unroll
  for (int ee = 0; ee < E_NUM; ++ee) {
    int c = counts[ee];
    int nmb = (c + 127) >> 7;
    if (e < 0 && mbl < cum + nmb) { e = ee; m0 = (mbl - cum) << 7; cnt = c; }
    cum += nmb;
  }
  if (e < 0) return;
  const int n0 = nb * 128;
  const int tid = threadIdx.x;

  __shared__ __align__(16) unsigned short As[128 * 64];
  __shared__ __align__(16) unsigned short Bt[128 * 64];
  __shared__ int rowp[128];
  __shared__ float roww[128];

  if (tid < 128) {
    int idx = m0 + tid;
    rowp[tid] = (idx < cnt) ? entries[e * T_TOK + idx] : -1;
    roww[tid] = (idx < cnt) ? entry_w[e * T_TOK + idx] : 0.f;
  }
  __syncthreads();

  const int w = tid >> 6, lane = tid & 63;
  const int lrow = lane >> 3, lchunk = lane & 7;
  const int jj = lchunk ^ lrow;

  const unsigned short* wo_e = wot + (size_t)e * H_DIM * I_DIM + (size_t)n0 * I_DIM;
  const unsigned short* gA[4]; unsigned short* lA[4];
  const unsigned short* gB[4]; unsigned short* lB[4];
#pragma unroll
  for (int t4 = 0; t4 < 4; ++t4) {
    int r = (t4 * 4 + w) * 8 + lrow;
    int p = rowp[r];
    int pr = (p >= 0) ? p : 0;
    gA[t4] = act + (size_t)pr * I_DIM + jj * 8;
    lA[t4] = As + (t4 * 4 + w) * 512;
    gB[t4] = wo_e + (size_t)r * I_DIM + jj * 8;
    lB[t4] = Bt + (t4 * 4 + w) * 512;
  }

  f32x4 acc[4][4];
#pragma unroll
  for (int i = 0; i < 4; ++i)
#pragma unroll
    for (int j = 0; j < 4; ++j) acc[i][j] = (f32x4){0.f, 0.f, 0.f, 0.f};

  const int msub = (w >> 1) * 64, nsub = (w & 1) * 64;
  const int fm = lane & 15, fq = lane >> 4;

  for (int kt = 0; kt < I_DIM; kt += 64) {
#pragma unroll
    for (int t4 = 0; t4 < 4; ++t4) {
      gl_lds16(gA[t4] + kt, lA[t4]);
      gl_lds16(gB[t4] + kt, lB[t4]);
    }
    __syncthreads();
#pragma unroll
    for (int ks = 0; ks < 64; ks += 32) {
      const int cb = (ks >> 3) + fq;
      bf16x8 a[4], b[4];
#pragma unroll
      for (int mi = 0; mi < 4; ++mi)
        a[mi] = FRAG(As, msub + mi * 16 + fm, cb);
#pragma unroll
      for (int ni = 0; ni < 4; ++ni)
        b[ni] = FRAG(Bt, nsub + ni * 16 + fm, cb);
#pragma unroll
      for (int mi = 0; mi < 4; ++mi)
#pragma unroll
        for (int ni = 0; ni < 4; ++ni)
          acc[mi][ni] = __builtin_amdgcn_mfma_f32_16x16x32_bf16(a[mi], b[ni], acc[mi][ni], 0, 0, 0);
    }
    __syncthreads();
  }
#pragma unroll
  for (int mi = 0; mi < 4; ++mi) {
#pragma unroll
    for (int r = 0; r < 4; ++r) {
      int ml = msub + mi * 16 + fq * 4 + r;
      int p = rowp[ml];
      if (p < 0) continue;
      float wt = roww[ml];
      float* dst = out + (size_t)(p >> 1) * H_DIM + n0 + nsub + fm;
#pragma unroll
      for (int ni = 0; ni < 4; ++ni)
        atomicAdd(dst + ni * 16, acc[mi][ni][r] * wt);
    }
  }
}

extern "C" void kernel_launch(void* const* d_in, const int* in_sizes, int n_in,
                              void* d_out, int out_size, void* d_ws, size_t ws_size,
                              hipStream_t stream) {
  const float* x   = (const float*)d_in[0];
  const float* wr  = (const float*)d_in[1];
  const float* wi0 = (const float*)d_in[2];
  const float* wi1 = (const float*)d_in[3];
  const float* wo  = (const float*)d_in[4];
  float* out = (float*)d_out;                       // [T,H] f32
  float* logits_out = out + (size_t)T_TOK * H_DIM;  // [T,E] f32

  char* w = (char*)d_ws;
  int* counts    = (int*)w;                                          // 64 B
  int* entries   = (int*)(w + 64);                                   // 128 KB
  float* entry_w = (float*)(w + 64 + (size_t)E_NUM * T_TOK * 4);     // 128 KB
  size_t off = 64 + 2 * (size_t)E_NUM * T_TOK * 4;
  unsigned short* xbf = (unsigned short*)(w + off); off += (size_t)T_TOK * H_DIM * 2;
  unsigned short* wgt = (unsigned short*)(w + off); off += (size_t)E_NUM * H_DIM * I_DIM * 2;
  unsigned short* wut = (unsigned short*)(w + off); off += (size_t)E_NUM * H_DIM * I_DIM * 2;
  unsigned short* wot = (unsigned short*)(w + off); off += (size_t)E_NUM * H_DIM * I_DIM * 2;
  unsigned short* act = (unsigned short*)(w + off);                  // [2T, I] bf16

  hipMemsetAsync(d_out, 0, (size_t)T_TOK * H_DIM * sizeof(float), stream);
  hipMemsetAsync(counts, 0, 64, stream);
  // merged: 3 weight transposes + router in one launch (all independent)
  prep_kernel<<<dim3(PREP_TOTAL), 256, 0, stream>>>(
      wi0, wi1, wo, wgt, wut, wot, x, wr, xbf, logits_out, counts, entries, entry_w);
  moe_up_kernel<<<dim3(MAX_MB * UP_NB), 256, 0, stream>>>(
      xbf, wgt, wut, counts, entries, act);
  moe_down_kernel<<<dim3(MAX_MB * DN_NB), 256, 0, stream>>>(
      act, wot, counts, entries, entry_w, out);
}

// Round 8
// 409.120 us; speedup vs baseline: 1.1002x; 1.0032x over previous
//
#include <hip/hip_runtime.h>

#define T_TOK 4096
#define H_DIM 2048
#define I_DIM 768
#define E_NUM 8

typedef __attribute__((ext_vector_type(8))) short bf16x8;
typedef __attribute__((ext_vector_type(4))) float f32x4;

__device__ __forceinline__ unsigned short f2bf(float f) {
  union { float f; unsigned int u; } c; c.f = f;
  unsigned int r = c.u + 0x7fffu + ((c.u >> 16) & 1u);
  return (unsigned short)(r >> 16);
}

// async global->LDS DMA, 16B per lane; lds dest = wave-uniform base + lane*16
__device__ __forceinline__ void gl_lds16(const unsigned short* g, unsigned short* l) {
  __builtin_amdgcn_global_load_lds(
      (const __attribute__((address_space(1))) unsigned int*)g,
      (__attribute__((address_space(3))) unsigned int*)l, 16, 0, 0);
}

// v8: router blocks FIRST (latency-bound, 1024 blocks @ RTOK=4), transposes
// after (BW-bound, 9216 blocks) -> the two phases overlap instead of
// serializing (R7: router ran as a 40us tail after the transposes).
#define RTOK 4
#define PREP_R (T_TOK / RTOK)             // 1024 router blocks, bids [0, PREP_R)
#define PREP_T0 (PREP_R + 3072)           // wi0 -> wgt
#define PREP_T1 (PREP_T0 + 3072)          // wi1 -> wut
#define PREP_T2 (PREP_T1 + 3072)          // wo  -> wot
#define PREP_TOTAL PREP_T2

struct RouterSmem {
  float red[RTOK][4][E_NUM];
  float lg[RTOK][E_NUM];
  int   ch_i[RTOK][2];
  float ch_w[RTOK][2];
};

// ---------------- merged prep: router (first) + 3 weight transposes ----------------
__global__ __launch_bounds__(256) void prep_kernel(
    const float* __restrict__ wi0, const float* __restrict__ wi1,
    const float* __restrict__ wo,
    unsigned short* __restrict__ wgt, unsigned short* __restrict__ wut,
    unsigned short* __restrict__ wot,
    const float* __restrict__ x, const float* __restrict__ wr,
    unsigned short* __restrict__ xbf, float* __restrict__ logits_out,
    int* __restrict__ counts, int* __restrict__ entries,
    float* __restrict__ entry_w)
{
  __shared__ __align__(16) char smem[64 * 65 * 4];
  const int bid = blockIdx.x;
  const int tid = threadIdx.x;

  if (bid >= PREP_R) {
    // ---- transpose job: f32 [E][K][N] -> bf16 [E][N][K] ----
    const float* src; unsigned short* dst; int K, N, lb;
    if (bid < PREP_T0)      { src = wi0; dst = wgt; K = H_DIM; N = I_DIM; lb = bid - PREP_R; }
    else if (bid < PREP_T1) { src = wi1; dst = wut; K = H_DIM; N = I_DIM; lb = bid - PREP_T0; }
    else                    { src = wo;  dst = wot; K = I_DIM; N = H_DIM; lb = bid - PREP_T1; }
    const int nx = N / 64, ky = K / 64;
    const int nb = (lb % nx) * 64;
    const int kb = ((lb / nx) % ky) * 64;
    const int e  = lb / (nx * ky);
    src += (size_t)e * K * N + (size_t)kb * N + nb;
    dst += (size_t)e * N * K + (size_t)nb * K + kb;
    float (*tile)[65] = (float(*)[65])smem;
    const int lr = tid >> 4, lc = (tid & 15) * 4;
#pragma unroll
    for (int it = 0; it < 4; ++it) {
      float4 v = *(const float4*)(src + (size_t)(lr + it * 16) * N + lc);
      tile[lr + it * 16][lc]     = v.x;
      tile[lr + it * 16][lc + 1] = v.y;
      tile[lr + it * 16][lc + 2] = v.z;
      tile[lr + it * 16][lc + 3] = v.w;
    }
    __syncthreads();
    const int wn = tid >> 2, wk = (tid & 3) * 16;
    union { uint4 u[2]; unsigned short h[16]; } o;
#pragma unroll
    for (int j = 0; j < 16; ++j) o.h[j] = f2bf(tile[wk + j][wn]);
    *(uint4*)(dst + (size_t)wn * K + wk)     = o.u[0];
    *(uint4*)(dst + (size_t)wn * K + wk + 8) = o.u[1];
    return;
  }

  // ---- router job (+ fused x f32->bf16 cast), RTOK=4 tokens per block ----
  RouterSmem* rs = (RouterSmem*)smem;
  const int w = tid >> 6, lane = tid & 63;
  const int t0 = bid * RTOK;
  const int hb = w * 512 + lane * 8;

  float wreg[8][8];
#pragma unroll
  for (int r = 0; r < 8; ++r) {
    *(float4*)&wreg[r][0] = *(const float4*)(wr + (size_t)(hb + r) * E_NUM);
    *(float4*)&wreg[r][4] = *(const float4*)(wr + (size_t)(hb + r) * E_NUM + 4);
  }

#pragma unroll
  for (int tt = 0; tt < RTOK; ++tt) {
    const int t = t0 + tt;
    float xv[8];
    *(float4*)&xv[0] = *(const float4*)(x + (size_t)t * H_DIM + hb);
    *(float4*)&xv[4] = *(const float4*)(x + (size_t)t * H_DIM + hb + 4);
    union { uint4 u; unsigned short h[8]; } o;
#pragma unroll
    for (int j = 0; j < 8; ++j) o.h[j] = f2bf(xv[j]);
    *(uint4*)(xbf + (size_t)t * H_DIM + hb) = o.u;

    float acc[E_NUM];
#pragma unroll
    for (int e = 0; e < E_NUM; ++e) acc[e] = 0.f;
#pragma unroll
    for (int r = 0; r < 8; ++r)
#pragma unroll
      for (int e = 0; e < E_NUM; ++e) acc[e] = fmaf(xv[r], wreg[r][e], acc[e]);
#pragma unroll
    for (int off = 32; off > 0; off >>= 1)
#pragma unroll
      for (int e = 0; e < E_NUM; ++e) acc[e] += __shfl_down(acc[e], off);
    if (lane == 0)
#pragma unroll
      for (int e = 0; e < E_NUM; ++e) rs->red[tt][w][e] = acc[e];
  }
  __syncthreads();

  if (tid < RTOK * E_NUM) {
    const int tt = tid >> 3, e = tid & 7;
    float l = rs->red[tt][0][e] + rs->red[tt][1][e] + rs->red[tt][2][e] + rs->red[tt][3][e];
    rs->lg[tt][e] = l;
    logits_out[(size_t)(t0 + tt) * E_NUM + e] = l;
  }
  __syncthreads();

  if (tid < RTOK) {
    const int tt = tid;
    float m1 = rs->lg[tt][0]; int i1 = 0;
#pragma unroll
    for (int e = 1; e < E_NUM; ++e) if (rs->lg[tt][e] > m1) { m1 = rs->lg[tt][e]; i1 = e; }
    float m2 = -3.4e38f; int i2 = -1;
#pragma unroll
    for (int e = 0; e < E_NUM; ++e) if (e != i1 && rs->lg[tt][e] > m2) { m2 = rs->lg[tt][e]; i2 = e; }
    float w1 = 1.f / (1.f + __expf(m2 - m1));
    rs->ch_i[tt][0] = i1; rs->ch_i[tt][1] = i2;
    rs->ch_w[tt][0] = w1; rs->ch_w[tt][1] = 1.f - w1;
  }
  __syncthreads();

  if (tid < E_NUM) {
    const int e = tid;
    int cnt = 0;
#pragma unroll
    for (int tt = 0; tt < RTOK; ++tt) {
      if (rs->ch_i[tt][0] == e) ++cnt;
      if (rs->ch_i[tt][1] == e) ++cnt;
    }
    if (cnt > 0) {
      int base = atomicAdd(&counts[e], cnt);
      int pos = 0;
#pragma unroll
      for (int tt = 0; tt < RTOK; ++tt) {
#pragma unroll
        for (int k = 0; k < 2; ++k) {
          if (rs->ch_i[tt][k] == e) {
            entries[e * T_TOK + base + pos] = (t0 + tt) * 2 + k;
            entry_w[e * T_TOK + base + pos] = rs->ch_w[tt][k];
            ++pos;
          }
        }
      }
    }
  }
}

// Fragment read from XOR-swizzled flat tile: row stride 64 shorts, chunk of 8
// physical chunk = logical ^ (row & 7)
#define FRAG(arr, row, cb) \
  (*(const bf16x8*)(&(arr)[((row) << 6) + ((((cb)) ^ ((row) & 7)) << 3)]))

#define MAX_MB 72
#define UP_NB (I_DIM / 64)        // 12 -> grid 864 = 8 * 108
#define DN_NB (H_DIM / 128)       // 16 -> grid 1152 = 8 * 144

// ---------------- Up-projection: act[p,:] = silu(x Wg) * (x Wu) ----------------
// v7 body kept: BM=128 BN=64 BK=64, single-buffer, 33KB LDS, compacted grid,
// T1 XCD-chunked swizzle (FETCH 158->80MB verified).
__global__ __launch_bounds__(256) void moe_up_kernel(
    const unsigned short* __restrict__ xbf,   // [T,H] bf16
    const unsigned short* __restrict__ wgt,   // [E][I][H] bf16
    const unsigned short* __restrict__ wut,   // [E][I][H] bf16
    const int* __restrict__ counts,
    const int* __restrict__ entries,
    unsigned short* __restrict__ act)         // [2T, I] bf16
{
  // XCD swizzle (bijective: 864 % 8 == 0)
  const int sb = (blockIdx.x & 7) * (MAX_MB * UP_NB / 8) + (blockIdx.x >> 3);
  const int nb = sb % UP_NB;                  // n innermost within chunk
  const int mbl = sb / UP_NB;
  int e = -1, m0 = 0, cnt = 0, cum = 0;
#pragma unroll
  for (int ee = 0; ee < E_NUM; ++ee) {
    int c = counts[ee];
    int nmb = (c + 127) >> 7;
    if (e < 0 && mbl < cum + nmb) { e = ee; m0 = (mbl - cum) << 7; cnt = c; }
    cum += nmb;
  }
  if (e < 0) return;
  const int n0 = nb * 64;
  const int tid = threadIdx.x;

  __shared__ __align__(16) unsigned short As[128 * 64];
  __shared__ __align__(16) unsigned short Bg[64 * 64];
  __shared__ __align__(16) unsigned short Bu[64 * 64];
  __shared__ int rowp[128];

  if (tid < 128) rowp[tid] = (m0 + tid < cnt) ? entries[e * T_TOK + m0 + tid] : -1;
  __syncthreads();

  const int w = tid >> 6, lane = tid & 63;
  const int lrow = lane >> 3, lchunk = lane & 7;
  const int jj = lchunk ^ lrow;              // swizzled global chunk (lane-const)

  const unsigned short* wg_e = wgt + (size_t)e * I_DIM * H_DIM + (size_t)n0 * H_DIM;
  const unsigned short* wu_e = wut + (size_t)e * I_DIM * H_DIM + (size_t)n0 * H_DIM;
  const unsigned short* gA[4];
  unsigned short* lA[4];
#pragma unroll
  for (int t4 = 0; t4 < 4; ++t4) {
    int r = (t4 * 4 + w) * 8 + lrow;         // 0..127
    int p = rowp[r];
    int tok = (p >= 0) ? (p >> 1) : 0;
    gA[t4] = xbf + (size_t)tok * H_DIM + jj * 8;
    lA[t4] = As + (t4 * 4 + w) * 512;        // 8 rows * 64 shorts
  }
  const unsigned short* gG[2]; const unsigned short* gU[2]; unsigned short* lG[2]; unsigned short* lU[2];
#pragma unroll
  for (int t2 = 0; t2 < 2; ++t2) {
    int r = (t2 * 4 + w) * 8 + lrow;         // 0..63
    gG[t2] = wg_e + (size_t)r * H_DIM + jj * 8;
    gU[t2] = wu_e + (size_t)r * H_DIM + jj * 8;
    lG[t2] = Bg + (t2 * 4 + w) * 512;
    lU[t2] = Bu + (t2 * 4 + w) * 512;
  }

  f32x4 accg[4][2], accu[4][2];
#pragma unroll
  for (int i = 0; i < 4; ++i)
#pragma unroll
    for (int j = 0; j < 2; ++j) {
      accg[i][j] = (f32x4){0.f, 0.f, 0.f, 0.f};
      accu[i][j] = (f32x4){0.f, 0.f, 0.f, 0.f};
    }

  const int msub = (w >> 1) * 64, nsub = (w & 1) * 32;
  const int fm = lane & 15, fq = lane >> 4;

  for (int kt = 0; kt < H_DIM; kt += 64) {
#pragma unroll
    for (int t4 = 0; t4 < 4; ++t4) gl_lds16(gA[t4] + kt, lA[t4]);
#pragma unroll
    for (int t2 = 0; t2 < 2; ++t2) {
      gl_lds16(gG[t2] + kt, lG[t2]);
      gl_lds16(gU[t2] + kt, lU[t2]);
    }
    __syncthreads();
#pragma unroll
    for (int ks = 0; ks < 64; ks += 32) {
      const int cb = (ks >> 3) + fq;
      bf16x8 a[4], bg[2], bu[2];
#pragma unroll
      for (int mi = 0; mi < 4; ++mi)
        a[mi] = FRAG(As, msub + mi * 16 + fm, cb);
#pragma unroll
      for (int ni = 0; ni < 2; ++ni) {
        bg[ni] = FRAG(Bg, nsub + ni * 16 + fm, cb);
        bu[ni] = FRAG(Bu, nsub + ni * 16 + fm, cb);
      }
#pragma unroll
      for (int mi = 0; mi < 4; ++mi)
#pragma unroll
        for (int ni = 0; ni < 2; ++ni) {
          accg[mi][ni] = __builtin_amdgcn_mfma_f32_16x16x32_bf16(a[mi], bg[ni], accg[mi][ni], 0, 0, 0);
          accu[mi][ni] = __builtin_amdgcn_mfma_f32_16x16x32_bf16(a[mi], bu[ni], accu[mi][ni], 0, 0, 0);
        }
    }
    __syncthreads();
  }
#pragma unroll
  for (int mi = 0; mi < 4; ++mi) {
#pragma unroll
    for (int r = 0; r < 4; ++r) {
      int ml = msub + mi * 16 + fq * 4 + r;
      int p = rowp[ml];
      if (p < 0) continue;
      size_t base = (size_t)p * I_DIM + n0 + nsub + fm;
#pragma unroll
      for (int ni = 0; ni < 2; ++ni) {
        float g = accg[mi][ni][r];
        float u = accu[mi][ni][r];
        float h = g / (1.f + __expf(-g)) * u;
        act[base + ni * 16] = f2bf(h);
      }
    }
  }
}

// ---------------- Down-projection + weighted scatter-add into d_out ----------------
// v7 body kept: BM=128 BN=128 BK=64, single-buffer + T1 XCD-chunked swizzle.
__global__ __launch_bounds__(256) void moe_down_kernel(
    const unsigned short* __restrict__ act,   // [2T, I] bf16
    const unsigned short* __restrict__ wot,   // [E][H][I] bf16
    const int* __restrict__ counts,
    const int* __restrict__ entries,
    const float* __restrict__ entry_w,
    float* __restrict__ out)                  // [T,H] f32
{
  // XCD swizzle (bijective: 1152 % 8 == 0)
  const int sb = (blockIdx.x & 7) * (MAX_MB * DN_NB / 8) + (blockIdx.x >> 3);
  const int nb = sb % DN_NB;                  // 16 n-blocks, innermost
  const int mbl = sb / DN_NB;
  int e = -1, m0 = 0, cnt = 0, cum = 0;
#pragma unroll
  for (int ee = 0; ee < E_NUM; ++ee) {
    int c = counts[ee];
    int nmb = (c + 127) >> 7;
    if (e < 0 && mbl < cum + nmb) { e = ee; m0 = (mbl - cum) << 7; cnt = c; }
    cum += nmb;
  }
  if (e < 0) return;
  const int n0 = nb * 128;
  const int tid = threadIdx.x;

  __shared__ __align__(16) unsigned short As[128 * 64];
  __shared__ __align__(16) unsigned short Bt[128 * 64];
  __shared__ int rowp[128];
  __shared__ float roww[128];

  if (tid < 128) {
    int idx = m0 + tid;
    rowp[tid] = (idx < cnt) ? entries[e * T_TOK + idx] : -1;
    roww[tid] = (idx < cnt) ? entry_w[e * T_TOK + idx] : 0.f;
  }
  __syncthreads();

  const int w = tid >> 6, lane = tid & 63;
  const int lrow = lane >> 3, lchunk = lane & 7;
  const int jj = lchunk ^ lrow;

  const unsigned short* wo_e = wot + (size_t)e * H_DIM * I_DIM + (size_t)n0 * I_DIM;
  const unsigned short* gA[4]; unsigned short* lA[4];
  const unsigned short* gB[4]; unsigned short* lB[4];
#pragma unroll
  for (int t4 = 0; t4 < 4; ++t4) {
    int r = (t4 * 4 + w) * 8 + lrow;
    int p = rowp[r];
    int pr = (p >= 0) ? p : 0;
    gA[t4] = act + (size_t)pr * I_DIM + jj * 8;
    lA[t4] = As + (t4 * 4 + w) * 512;
    gB[t4] = wo_e + (size_t)r * I_DIM + jj * 8;
    lB[t4] = Bt + (t4 * 4 + w) * 512;
  }

  f32x4 acc[4][4];
#pragma unroll
  for (int i = 0; i < 4; ++i)
#pragma unroll
    for (int j = 0; j < 4; ++j) acc[i][j] = (f32x4){0.f, 0.f, 0.f, 0.f};

  const int msub = (w >> 1) * 64, nsub = (w & 1) * 64;
  const int fm = lane & 15, fq = lane >> 4;

  for (int kt = 0; kt < I_DIM; kt += 64) {
#pragma unroll
    for (int t4 = 0; t4 < 4; ++t4) {
      gl_lds16(gA[t4] + kt, lA[t4]);
      gl_lds16(gB[t4] + kt, lB[t4]);
    }
    __syncthreads();
#pragma unroll
    for (int ks = 0; ks < 64; ks += 32) {
      const int cb = (ks >> 3) + fq;
      bf16x8 a[4], b[4];
#pragma unroll
      for (int mi = 0; mi < 4; ++mi)
        a[mi] = FRAG(As, msub + mi * 16 + fm, cb);
#pragma unroll
      for (int ni = 0; ni < 4; ++ni)
        b[ni] = FRAG(Bt, nsub + ni * 16 + fm, cb);
#pragma unroll
      for (int mi = 0; mi < 4; ++mi)
#pragma unroll
        for (int ni = 0; ni < 4; ++ni)
          acc[mi][ni] = __builtin_amdgcn_mfma_f32_16x16x32_bf16(a[mi], b[ni], acc[mi][ni], 0, 0, 0);
    }
    __syncthreads();
  }
#pragma unroll
  for (int mi = 0; mi < 4; ++mi) {
#pragma unroll
    for (int r = 0; r < 4; ++r) {
      int ml = msub + mi * 16 + fq * 4 + r;
      int p = rowp[ml];
      if (p < 0) continue;
      float wt = roww[ml];
      float* dst = out + (size_t)(p >> 1) * H_DIM + n0 + nsub + fm;
#pragma unroll
      for (int ni = 0; ni < 4; ++ni)
        atomicAdd(dst + ni * 16, acc[mi][ni][r] * wt);
    }
  }
}

extern "C" void kernel_launch(void* const* d_in, const int* in_sizes, int n_in,
                              void* d_out, int out_size, void* d_ws, size_t ws_size,
                              hipStream_t stream) {
  const float* x   = (const float*)d_in[0];
  const float* wr  = (const float*)d_in[1];
  const float* wi0 = (const float*)d_in[2];
  const float* wi1 = (const float*)d_in[3];
  const float* wo  = (const float*)d_in[4];
  float* out = (float*)d_out;                       // [T,H] f32
  float* logits_out = out + (size_t)T_TOK * H_DIM;  // [T,E] f32

  char* w = (char*)d_ws;
  int* counts    = (int*)w;                                          // 64 B
  int* entries   = (int*)(w + 64);                                   // 128 KB
  float* entry_w = (float*)(w + 64 + (size_t)E_NUM * T_TOK * 4);     // 128 KB
  size_t off = 64 + 2 * (size_t)E_NUM * T_TOK * 4;
  unsigned short* xbf = (unsigned short*)(w + off); off += (size_t)T_TOK * H_DIM * 2;
  unsigned short* wgt = (unsigned short*)(w + off); off += (size_t)E_NUM * H_DIM * I_DIM * 2;
  unsigned short* wut = (unsigned short*)(w + off); off += (size_t)E_NUM * H_DIM * I_DIM * 2;
  unsigned short* wot = (unsigned short*)(w + off); off += (size_t)E_NUM * H_DIM * I_DIM * 2;
  unsigned short* act = (unsigned short*)(w + off);                  // [2T, I] bf16

  hipMemsetAsync(d_out, 0, (size_t)T_TOK * H_DIM * sizeof(float), stream);
  hipMemsetAsync(counts, 0, 64, stream);
  // merged prep: router first (overlaps with the BW-bound transposes)
  prep_kernel<<<dim3(PREP_TOTAL), 256, 0, stream>>>(
      wi0, wi1, wo, wgt, wut, wot, x, wr, xbf, logits_out, counts, entries, entry_w);
  moe_up_kernel<<<dim3(MAX_MB * UP_NB), 256, 0, stream>>>(
      xbf, wgt, wut, counts, entries, act);
  moe_down_kernel<<<dim3(MAX_MB * DN_NB), 256, 0, stream>>>(
      act, wot, counts, entries, entry_w, out);
}